// Round 16
// baseline (327.190 us; speedup 1.0000x reference)
//
#include <hip/hip_runtime.h>
#include <stdint.h>

#define B_ 8
#define C_ 256
#define N_ 2048
#define HC 128

typedef float f32x4 __attribute__((ext_vector_type(4)));
typedef short s16x8 __attribute__((ext_vector_type(8)));

__device__ __forceinline__ unsigned short f2bf(float f){
  union { float f; unsigned u; } v; v.f = f;
  unsigned r = v.u + 0x7FFF + ((v.u >> 16) & 1u);
  return (unsigned short)(r >> 16);
}
__device__ __forceinline__ float bf2f(unsigned short u){
  union { unsigned u; float f; } v; v.u = ((unsigned)u) << 16;
  return v.f;
}
__device__ __forceinline__ void gload_lds16(const void* g, void* l){
  __builtin_amdgcn_global_load_lds(
      (const __attribute__((address_space(1))) unsigned int*)g,
      (__attribute__((address_space(3))) unsigned int*)l, 16, 0, 0);
}

// ---------------- prep: weights -> bf16, BN affine fold ----------------
struct PrepArgs {
  const float *s0,*s1,*s2,*s3,*s4,*s5;
  unsigned short *d0,*d1,*d2,*d3,*d4,*d5;
  const float *b1,*g1,*be1,*m1,*v1;
  const float *b2,*g2,*be2,*m2,*v2;
  float *sc1,*sh1,*sc2,*sh2;
};

__global__ __launch_bounds__(256) void k_prep(PrepArgs a){
  int gid = blockIdx.x*256 + threadIdx.x;
  const int S0=65536, S1=131072, S2=196608, S3=229376, S4=245760, S5=278528;
  if (gid < S0)      a.d0[gid]    = f2bf(a.s0[gid]);
  else if (gid < S1) a.d1[gid-S0] = f2bf(a.s1[gid-S0]);
  else if (gid < S2) a.d2[gid-S1] = f2bf(a.s2[gid-S1]);
  else if (gid < S3) a.d3[gid-S2] = f2bf(a.s3[gid-S2]);
  else if (gid < S4) a.d4[gid-S3] = f2bf(a.s4[gid-S3]);
  else if (gid < S5) a.d5[gid-S4] = f2bf(a.s5[gid-S4]);
  else if (gid < S5+128){
    int o = gid - S5;
    float inv = a.g1[o] * rsqrtf(a.v1[o] + 1e-5f);
    a.sc1[o] = inv;
    a.sh1[o] = a.b1[o]*inv + a.be1[o] - a.m1[o]*inv;
  } else if (gid < S5+256){
    int o = gid - S5 - 128;
    float inv = a.g2[o] * rsqrtf(a.v2[o] + 1e-5f);
    a.sc2[o] = inv;
    a.sh2[o] = a.b2[o]*inv + a.be2[o] - a.m2[o]*inv;
  }
}

// ---------------- fused: x-transpose + QKV GEMM (z-split for parallelism) ----
__global__ __launch_bounds__(256) void k_qkv(
    const float* __restrict__ x,
    const unsigned short* __restrict__ wqb, const unsigned short* __restrict__ wkb,
    const unsigned short* __restrict__ wvb,
    const float* __restrict__ bq, const float* __restrict__ bk, const float* __restrict__ bv,
    unsigned short* __restrict__ Qn, unsigned short* __restrict__ Kn,
    unsigned short* __restrict__ Vc)
{
  __shared__ unsigned short Alds[64][256];
  __shared__ unsigned short Tlds[64][260];
  int b = blockIdx.y, nt = blockIdx.x, z = blockIdx.z;
  int nb = nt*64;
  const float* xb = x + (size_t)b*C_*N_;
  int tid = threadIdx.x;
  float* Tf = (float*)&Tlds[0][0];   // [64][65]
  int tn = tid & 63, tq = tid >> 6;
  for (int c0 = 0; c0 < 256; c0 += 64){
    #pragma unroll
    for (int cc = tq; cc < 64; cc += 4)
      Tf[tn*65 + cc] = xb[(size_t)(c0+cc)*N_ + nb + tn];
    __syncthreads();
    #pragma unroll
    for (int nl = tq; nl < 64; nl += 4){
      int c = c0 + tn;
      Alds[nl][c ^ ((nl&7)<<3)] = f2bf(Tf[nl*65 + tn]);
    }
    __syncthreads();
  }
  int w = tid >> 6, l = tid & 63, lr = l & 15, lq = l >> 4;
  const unsigned short* W = (z==0) ? wqb : (z==1 ? wkb : wvb);
  const float* bias = (z==0) ? bq : (z==1 ? bk : bv);
  f32x4 zero = {0.f,0.f,0.f,0.f};
  f32x4 acc[16];
  #pragma unroll
  for (int i=0;i<16;i++) acc[i] = zero;
  #pragma unroll
  for (int ks = 0; ks < 8; ks++){
    s16x8 a = *(const s16x8*)&Alds[16*w + lr][(32*ks + 8*lq) ^ ((lr&7)<<3)];
    #pragma unroll
    for (int ct = 0; ct < 16; ct++){
      s16x8 bw = *(const s16x8*)&W[(size_t)(16*ct + lr)*C_ + 32*ks + 8*lq];
      acc[ct] = __builtin_amdgcn_mfma_f32_16x16x32_bf16(a, bw, acc[ct], 0, 0, 0);
    }
  }
  if (z < 2){
    unsigned short* ob = (z==0 ? Qn : Kn) + ((size_t)b*N_ + nb)*C_;
    #pragma unroll
    for (int ct = 0; ct < 16; ct++){
      int o = 16*ct + lr;
      float bi = bias[o];
      #pragma unroll
      for (int r = 0; r < 4; r++){
        int row = 16*w + 4*lq + r;
        ob[(size_t)row*C_ + o] = f2bf(acc[ct][r] + bi);
      }
    }
  } else {
    __syncthreads();
    #pragma unroll
    for (int ct = 0; ct < 16; ct++){
      int o = 16*ct + lr;
      float bi = bias[o];
      #pragma unroll
      for (int r = 0; r < 4; r++)
        Tlds[16*w + 4*lq + r][o] = f2bf(acc[ct][r] + bi);
    }
    __syncthreads();
    unsigned short* vb = Vc + (size_t)b*C_*N_;
    int j = tid & 63, o0 = tid >> 6;
    #pragma unroll
    for (int o = o0; o < 256; o += 4)
      vb[(size_t)o*N_ + nb + j] = Tlds[j][o];
  }
}

// ---------------- attention: 16x16 frags, q-tile 64, 40KB LDS -> 4 blocks/CU ----
// grid 1024 x 256 thr = exactly 4 blocks/CU (4 x 40960 = 163840 = full pool).
// Single beta buffer [64 q][32 m] f32; each wave's P scratch ALIASES its own
// 2KB row-slice of the beta buffer (written only after that wave consumed its
// beta values; other waves never touch those rows; next tile's beta DMA is
// issued after barrier A when all P reads are complete). beta(t+1)/K/V(t+1)
// staged between barrier A and the bottom __syncthreads; the exposed HBM
// latency within a block is covered by the other 3 co-resident blocks.
__global__ __launch_bounds__(256, 4) void k_attn(
    const unsigned short* __restrict__ Qn, const unsigned short* __restrict__ Kn,
    const unsigned short* __restrict__ Vc, const float* __restrict__ beta,
    unsigned short* __restrict__ Opb, float* __restrict__ Ls)
{
  __shared__ __align__(16) char smem[40960];
  unsigned short* Klds = (unsigned short*)smem;             // 16 KB [32 m][256 c]
  unsigned short* Vt   = (unsigned short*)(smem + 16384);   // 16 KB [256 c][32 m]
  float*          Bl   = (float*)(smem + 32768);            //  8 KB [64 q][32 m]
  const int tid = threadIdx.x;
  const int bid = blockIdx.x;
  const int b = bid & 7;
  const int jj = bid >> 3;                 // 0..127
  const int nt = jj & 31, mh = jj >> 5;    // nt 0..31, mh 0..3
  const int nb = nt*64;
  const unsigned short* Qb = Qn + (size_t)b*N_*C_;
  const unsigned short* Kb = Kn + (size_t)b*N_*C_;
  const unsigned short* Vb = Vc + (size_t)b*C_*N_;
  const float* betab = beta + (size_t)b*N_*N_;
  const int w = tid >> 6, lane = tid & 63, lr = lane & 15, lq = lane >> 4;
  const int wbase = (tid & ~63) * 16;
  // per-wave P scratch: aliases THIS wave's 16 beta rows (2KB each)
  unsigned short* Pw = (unsigned short*)((char*)Bl + w*2048);

  // Q A-frags: qf[ks] = Q[nb+16w+lr][32ks+8lq .. +8]  (regs whole kernel)
  s16x8 qf[8];
  {
    const unsigned short* qp = Qb + (size_t)(nb + 16*w + lr)*C_ + 8*lq;
    #pragma unroll
    for (int ks = 0; ks < 8; ks++)
      qf[ks] = *(const s16x8*)&qp[32*ks];
  }
  f32x4 zero = {0.f,0.f,0.f,0.f};
  f32x4 oacc[16];
  #pragma unroll
  for (int i=0;i<16;i++) oacc[i] = zero;
  float psum[4] = {0.f,0.f,0.f,0.f};

// K: LDS[row][slot16B] = K[mb+row][(slot^(row&31))*8 .. +8)  (32 rows x 32 slots)
#define STAGEK(MB) { \
  _Pragma("unroll") \
  for (int rr=0; rr<4; rr++){ \
    const int o_ = rr*4096 + tid*16; \
    const int row_ = o_ >> 9; \
    const int slot_ = (o_ >> 4) & 31; \
    gload_lds16(Kb + (size_t)((MB)+row_)*C_ + ((slot_ ^ (row_&31))<<3), \
                (char*)Klds + rr*4096 + wbase); } }
// V: LDS[c][slot16B] = V[c][(MB) + (slot^(c&3))*8 .. +8)   (256 c x 4 slots)
#define STAGEV(MB) { \
  _Pragma("unroll") \
  for (int rr=0; rr<4; rr++){ \
    const int o_ = rr*4096 + tid*16; \
    const int c_ = o_ >> 6; \
    const int slot_ = (o_ >> 4) & 3; \
    gload_lds16(Vb + (size_t)c_*N_ + (MB) + ((slot_ ^ (c_&3))<<3), \
                (char*)Vt + rr*4096 + wbase); } }
// beta: Bl[q][m] f32 linear  (64 q x 32 m = 8KB, 2 loads/thread)
#define STAGEB(MB) { \
  _Pragma("unroll") \
  for (int rr=0; rr<2; rr++){ \
    const int o_ = rr*4096 + tid*16; \
    const int row_ = o_ >> 7; \
    const int g_ = (o_ >> 4) & 7; \
    gload_lds16(betab + (size_t)(nb+row_)*N_ + (MB) + g_*4, \
                (char*)Bl + rr*4096 + wbase); } }

  // prologue: K(0), V(0), beta(0)
  STAGEK(mh*512)
  STAGEV(mh*512)
  STAGEB(mh*512)
  __syncthreads();

  for (int mt = 0; mt < 16; mt++){
    const int mb = mh*512 + mt*32;
    // beta(mt) from this wave's own rows of Bl
    f32x4 bv[2];
    #pragma unroll
    for (int ct=0; ct<2; ct++){
      // bv[ct][r] = beta[16w+4lq+r][16ct+lr] gathered as 4 scalar reads
      #pragma unroll
      for (int r=0; r<4; r++)
        bv[ct][r] = Bl[(16*w + 4*lq + r)*32 + 16*ct + lr];
    }
    // S = Q K^T : S[q=16w+4lq+r][m=16ct+lr]
    f32x4 sacc[2];
    sacc[0] = zero; sacc[1] = zero;
    __builtin_amdgcn_s_setprio(1);
    #pragma unroll
    for (int ks=0; ks<8; ks++){
      #pragma unroll
      for (int ct=0; ct<2; ct++){
        const int row = 16*ct + lr;
        const s16x8 kf = *(const s16x8*)
            &Klds[row*256 + (((4*ks + lq) ^ (row&31)) << 3)];
        sacc[ct] = __builtin_amdgcn_mfma_f32_16x16x32_bf16(qf[ks], kf, sacc[ct], 0,0,0);
      }
    }
    __builtin_amdgcn_s_setprio(0);
    // P = exp(S*beta); psum partial; pack to per-wave scratch (own beta rows,
    // safe: this thread's bv reads precede these writes in program order)
    #pragma unroll
    for (int ct=0; ct<2; ct++)
      #pragma unroll
      for (int r=0; r<4; r++){
        float p = __expf(sacc[ct][r] * bv[ct][r]);
        psum[r] += p;
        Pw[(4*lq + r)*40 + 16*ct + lr] = f2bf(p);
      }
    // PV: O[q][c] += P[q][m] V[c][m]   (K=32, one MFMA per ct)
    {
      const s16x8 pf = *(const s16x8*)&Pw[lr*40 + 8*lq];
      __builtin_amdgcn_s_setprio(1);
      #pragma unroll
      for (int ct=0; ct<16; ct++){
        const int c = 16*ct + lr;
        const s16x8 vf = *(const s16x8*)
            &Vt[c*32 + ((lq ^ (c&3)) << 3)];
        oacc[ct] = __builtin_amdgcn_mfma_f32_16x16x32_bf16(pf, vf, oacc[ct], 0,0,0);
      }
      __builtin_amdgcn_s_setprio(0);
    }
    // barrier A: ALL waves' LDS reads (beta, K, V, P) for tile mt are done
    asm volatile("s_waitcnt lgkmcnt(0)" ::: "memory");
    __builtin_amdgcn_s_barrier();
    // stage next tile (K, V, beta) -- beta overwrites Bl incl. P scratch, safe
    if (mt + 1 < 16){
      STAGEK(mb + 32)
      STAGEV(mb + 32)
      STAGEB(mb + 32)
    }
    __syncthreads();   // drains all staging DMAs
  }
#undef STAGEK
#undef STAGEV
#undef STAGEB

  // psum reduce over the 16-lane lr group (lanes share (w,lq) -> same q rows)
  #pragma unroll
  for (int r=0;r<4;r++){
    #pragma unroll
    for (int d=1; d<16; d<<=1) psum[r] += __shfl_xor(psum[r], d, 64);
  }
  // store unnormalized bf16 partials
  unsigned short* Ob = Opb + ((size_t)mh*8 + b)*(size_t)N_*C_;
  #pragma unroll
  for (int ct=0; ct<16; ct++){
    const int c = 16*ct + lr;
    #pragma unroll
    for (int r=0; r<4; r++){
      const int qo = nb + 16*w + 4*lq + r;
      Ob[(size_t)qo*C_ + c] = f2bf(oacc[ct][r]);
    }
  }
  if (lr == 0){
    float* Lb = Ls + ((size_t)mh*8 + b)*N_;
    #pragma unroll
    for (int r=0;r<4;r++) Lb[nb + 16*w + 4*lq + r] = psum[r];
  }
}

// ---------------- fused MLP: merge+normalize -> conv1(BN,ReLU) -> conv2(BN,ReLU)
// -> conv3(+bias) -> residual add, all through LDS (overlaid phases).
__global__ __launch_bounds__(256) void k_mlpf(
    const unsigned short* __restrict__ Opb, const float* __restrict__ Ls,
    const unsigned short* __restrict__ W1, const float* __restrict__ sc1,
    const float* __restrict__ sh1,
    const unsigned short* __restrict__ W2, const float* __restrict__ sc2,
    const float* __restrict__ sh2,
    const unsigned short* __restrict__ W3, const float* __restrict__ b3,
    const float* __restrict__ x, float* __restrict__ out)
{
  __shared__ __align__(16) char smem[65792];
  unsigned short* Alds = (unsigned short*)smem;            // [64][256] @0 (phase1)
  unsigned short* H2   = (unsigned short*)(smem + 33024);  // [64][128]
  unsigned short* H1   = (unsigned short*)(smem + 49408);  // [64][128]
  float*          Dlds = (float*)smem;                     // [64][129] (phase3)
  int b = blockIdx.y, nt = blockIdx.x, nb = nt*64;
  int tid = threadIdx.x;
  const size_t PS = (size_t)8*N_*C_;
  for (int i = tid; i < 64*32; i += 256){
    int r = i >> 5, cv = i & 31;
    int row = nb + r;
    float ls = Ls[(size_t)b*N_ + row] + Ls[(size_t)(8+b)*N_ + row]
             + Ls[(size_t)(16+b)*N_ + row] + Ls[(size_t)(24+b)*N_ + row];
    float inv = 1.f / ls;
    size_t base = ((size_t)b*N_ + row)*C_ + cv*8;
    float a8[8] = {0.f,0.f,0.f,0.f,0.f,0.f,0.f,0.f};
    #pragma unroll
    for (int m=0;m<4;m++){
      s16x8 v = *(const s16x8*)&Opb[(size_t)m*PS + base];
      #pragma unroll
      for (int j=0;j<8;j++) a8[j] += bf2f((unsigned short)v[j]);
    }
    s16x8 o;
    #pragma unroll
    for (int j=0;j<8;j++) o[j] = (short)f2bf(a8[j] * inv);
    *(s16x8*)&Alds[r*256 + ((cv*8) ^ ((r&7)<<3))] = o;
  }
  __syncthreads();
  int w = tid >> 6, l = tid & 63, lr = l & 15, lq = l >> 4;
  f32x4 zero = {0.f,0.f,0.f,0.f};
  {
    f32x4 acc[8];
    #pragma unroll
    for (int i=0;i<8;i++) acc[i] = zero;
    #pragma unroll
    for (int ks = 0; ks < 8; ks++){
      s16x8 a = *(const s16x8*)&Alds[(16*w + lr)*256 + ((32*ks + 8*lq) ^ ((lr&7)<<3))];
      #pragma unroll
      for (int ct = 0; ct < 8; ct++){
        s16x8 bw = *(const s16x8*)&W1[(size_t)(16*ct + lr)*C_ + 32*ks + 8*lq];
        acc[ct] = __builtin_amdgcn_mfma_f32_16x16x32_bf16(a, bw, acc[ct], 0, 0, 0);
      }
    }
    __syncthreads();
    #pragma unroll
    for (int ct = 0; ct < 8; ct++){
      int o = 16*ct + lr;
      float s_ = sc1[o], h_ = sh1[o];
      #pragma unroll
      for (int r = 0; r < 4; r++){
        int row = 16*w + 4*lq + r;
        H1[row*128 + (o ^ ((row&7)<<3))] = f2bf(fmaxf(acc[ct][r]*s_ + h_, 0.f));
      }
    }
  }
  __syncthreads();
  {
    f32x4 acc[8];
    #pragma unroll
    for (int i=0;i<8;i++) acc[i] = zero;
    #pragma unroll
    for (int ks = 0; ks < 4; ks++){
      s16x8 a = *(const s16x8*)&H1[(16*w + lr)*128 + ((32*ks + 8*lq) ^ ((lr&7)<<3))];
      #pragma unroll
      for (int ct = 0; ct < 8; ct++){
        s16x8 bw = *(const s16x8*)&W2[(size_t)(16*ct + lr)*HC + 32*ks + 8*lq];
        acc[ct] = __builtin_amdgcn_mfma_f32_16x16x32_bf16(a, bw, acc[ct], 0, 0, 0);
      }
    }
    __syncthreads();
    #pragma unroll
    for (int ct = 0; ct < 8; ct++){
      int o = 16*ct + lr;
      float s_ = sc2[o], h_ = sh2[o];
      #pragma unroll
      for (int r = 0; r < 4; r++){
        int row = 16*w + 4*lq + r;
        H2[row*128 + (o ^ ((row&7)<<3))] = f2bf(fmaxf(acc[ct][r]*s_ + h_, 0.f));
      }
    }
  }
  __syncthreads();
  f32x4 acc[16];
  #pragma unroll
  for (int i=0;i<16;i++) acc[i] = zero;
  #pragma unroll
  for (int ks = 0; ks < 4; ks++){
    s16x8 a = *(const s16x8*)&H2[(16*w + lr)*128 + ((32*ks + 8*lq) ^ ((lr&7)<<3))];
    #pragma unroll
    for (int ct = 0; ct < 16; ct++){
      s16x8 bw = *(const s16x8*)&W3[(size_t)(16*ct + lr)*HC + 32*ks + 8*lq];
      acc[ct] = __builtin_amdgcn_mfma_f32_16x16x32_bf16(a, bw, acc[ct], 0, 0, 0);
    }
  }
  const float* xb = x + (size_t)b*C_*N_;
  float* ob = out + (size_t)b*C_*N_;
  int j = tid & 63, o0 = tid >> 6;
  #pragma unroll
  for (int half = 0; half < 2; half++){
    __syncthreads();
    #pragma unroll
    for (int ct = 8*half; ct < 8*half+8; ct++){
      int o = 16*ct + lr;
      float bi = b3[o];
      #pragma unroll
      for (int r = 0; r < 4; r++){
        int row = 16*w + 4*lq + r;
        Dlds[row*129 + (o - 128*half)] = acc[ct][r] + bi;
      }
    }
    __syncthreads();
    for (int o = 128*half + o0; o < 128*half + 128; o += 4)
      ob[(size_t)o*N_ + nb + j] = xb[(size_t)o*N_ + nb + j]
                                + Dlds[j*129 + (o - 128*half)];
  }
}

extern "C" void kernel_launch(void* const* d_in, const int* in_sizes, int n_in,
                              void* d_out, int out_size, void* d_ws, size_t ws_size,
                              hipStream_t stream)
{
  const float* x    = (const float*)d_in[0];
  const float* beta = (const float*)d_in[1];
  const float* wq = (const float*)d_in[2];  const float* bq = (const float*)d_in[3];
  const float* wk = (const float*)d_in[4];  const float* bk = (const float*)d_in[5];
  const float* wv = (const float*)d_in[6];  const float* bv = (const float*)d_in[7];
  const float* w1 = (const float*)d_in[8];  const float* b1 = (const float*)d_in[9];
  const float* g1 = (const float*)d_in[10]; const float* be1= (const float*)d_in[11];
  const float* m1 = (const float*)d_in[12]; const float* v1 = (const float*)d_in[13];
  const float* w2 = (const float*)d_in[14]; const float* b2 = (const float*)d_in[15];
  const float* g2 = (const float*)d_in[16]; const float* be2= (const float*)d_in[17];
  const float* m2 = (const float*)d_in[18]; const float* v2 = (const float*)d_in[19];
  const float* w3 = (const float*)d_in[20]; const float* b3 = (const float*)d_in[21];

  char* p = (char*)d_ws;
  auto alloc = [&](size_t n){ char* r = p; p += (n + 255) & ~(size_t)255; return r; };
  unsigned short* Qn  = (unsigned short*)alloc((size_t)B_*N_*C_*2);
  unsigned short* Kn  = (unsigned short*)alloc((size_t)B_*N_*C_*2);
  unsigned short* Vc  = (unsigned short*)alloc((size_t)B_*N_*C_*2);
  unsigned short* Opb = (unsigned short*)alloc((size_t)4*B_*N_*C_*2);
  float* Ls = (float*)alloc((size_t)4*B_*N_*4);
  unsigned short* wqb = (unsigned short*)alloc(65536*2);
  unsigned short* wkb = (unsigned short*)alloc(65536*2);
  unsigned short* wvb = (unsigned short*)alloc(65536*2);
  unsigned short* w1b = (unsigned short*)alloc(32768*2);
  unsigned short* w2b = (unsigned short*)alloc(16384*2);
  unsigned short* w3b = (unsigned short*)alloc(32768*2);
  float* sc1 = (float*)alloc(128*4);
  float* sh1 = (float*)alloc(128*4);
  float* sc2 = (float*)alloc(128*4);
  float* sh2 = (float*)alloc(128*4);

  PrepArgs pa;
  pa.s0 = wq; pa.s1 = wk; pa.s2 = wv; pa.s3 = w1; pa.s4 = w2; pa.s5 = w3;
  pa.d0 = wqb; pa.d1 = wkb; pa.d2 = wvb; pa.d3 = w1b; pa.d4 = w2b; pa.d5 = w3b;
  pa.b1 = b1; pa.g1 = g1; pa.be1 = be1; pa.m1 = m1; pa.v1 = v1;
  pa.b2 = b2; pa.g2 = g2; pa.be2 = be2; pa.m2 = m2; pa.v2 = v2;
  pa.sc1 = sc1; pa.sh1 = sh1; pa.sc2 = sc2; pa.sh2 = sh2;

  k_prep<<<dim3(1089), dim3(256), 0, stream>>>(pa);
  k_qkv<<<dim3(32, 8, 3), dim3(256), 0, stream>>>(x, wqb, wkb, wvb, bq, bk, bv, Qn, Kn, Vc);
  k_attn<<<dim3(1024), dim3(256), 0, stream>>>(Qn, Kn, Vc, beta, Opb, Ls);
  k_mlpf<<<dim3(32, 8), dim3(256), 0, stream>>>(Opb, Ls, w1b, sc1, sh1,
                                                w2b, sc2, sh2, w3b, b3,
                                                x, (float*)d_out);
}

// Round 17
// 322.823 us; speedup vs baseline: 1.0135x; 1.0135x over previous
//
#include <hip/hip_runtime.h>
#include <stdint.h>

#define B_ 8
#define C_ 256
#define N_ 2048
#define HC 128

typedef float f32x4 __attribute__((ext_vector_type(4)));
typedef short s16x8 __attribute__((ext_vector_type(8)));

__device__ __forceinline__ unsigned short f2bf(float f){
  union { float f; unsigned u; } v; v.f = f;
  unsigned r = v.u + 0x7FFF + ((v.u >> 16) & 1u);
  return (unsigned short)(r >> 16);
}
__device__ __forceinline__ float bf2f(unsigned short u){
  union { unsigned u; float f; } v; v.u = ((unsigned)u) << 16;
  return v.f;
}
__device__ __forceinline__ void gload_lds16(const void* g, void* l){
  __builtin_amdgcn_global_load_lds(
      (const __attribute__((address_space(1))) unsigned int*)g,
      (__attribute__((address_space(3))) unsigned int*)l, 16, 0, 0);
}
// NT (non-temporal, CPol bit1) variant: streaming loads evict-first in L2,
// so the beta stream does not displace the K/V working set.
__device__ __forceinline__ void gload_lds16_nt(const void* g, void* l){
  __builtin_amdgcn_global_load_lds(
      (const __attribute__((address_space(1))) unsigned int*)g,
      (__attribute__((address_space(3))) unsigned int*)l, 16, 0, 2);
}

// ---------------- prep: weights -> bf16, BN affine fold ----------------
struct PrepArgs {
  const float *s0,*s1,*s2,*s3,*s4,*s5;
  unsigned short *d0,*d1,*d2,*d3,*d4,*d5;
  const float *b1,*g1,*be1,*m1,*v1;
  const float *b2,*g2,*be2,*m2,*v2;
  float *sc1,*sh1,*sc2,*sh2;
};

__global__ __launch_bounds__(256) void k_prep(PrepArgs a){
  int gid = blockIdx.x*256 + threadIdx.x;
  const int S0=65536, S1=131072, S2=196608, S3=229376, S4=245760, S5=278528;
  if (gid < S0)      a.d0[gid]    = f2bf(a.s0[gid]);
  else if (gid < S1) a.d1[gid-S0] = f2bf(a.s1[gid-S0]);
  else if (gid < S2) a.d2[gid-S1] = f2bf(a.s2[gid-S1]);
  else if (gid < S3) a.d3[gid-S2] = f2bf(a.s3[gid-S2]);
  else if (gid < S4) a.d4[gid-S3] = f2bf(a.s4[gid-S3]);
  else if (gid < S5) a.d5[gid-S4] = f2bf(a.s5[gid-S4]);
  else if (gid < S5+128){
    int o = gid - S5;
    float inv = a.g1[o] * rsqrtf(a.v1[o] + 1e-5f);
    a.sc1[o] = inv;
    a.sh1[o] = a.b1[o]*inv + a.be1[o] - a.m1[o]*inv;
  } else if (gid < S5+256){
    int o = gid - S5 - 128;
    float inv = a.g2[o] * rsqrtf(a.v2[o] + 1e-5f);
    a.sc2[o] = inv;
    a.sh2[o] = a.b2[o]*inv + a.be2[o] - a.m2[o]*inv;
  }
}

// ---------------- fused: x-transpose + QKV GEMM (z-split for parallelism) ----
__global__ __launch_bounds__(256) void k_qkv(
    const float* __restrict__ x,
    const unsigned short* __restrict__ wqb, const unsigned short* __restrict__ wkb,
    const unsigned short* __restrict__ wvb,
    const float* __restrict__ bq, const float* __restrict__ bk, const float* __restrict__ bv,
    unsigned short* __restrict__ Qn, unsigned short* __restrict__ Kn,
    unsigned short* __restrict__ Vc)
{
  __shared__ unsigned short Alds[64][256];
  __shared__ unsigned short Tlds[64][260];
  int b = blockIdx.y, nt = blockIdx.x, z = blockIdx.z;
  int nb = nt*64;
  const float* xb = x + (size_t)b*C_*N_;
  int tid = threadIdx.x;
  float* Tf = (float*)&Tlds[0][0];   // [64][65]
  int tn = tid & 63, tq = tid >> 6;
  for (int c0 = 0; c0 < 256; c0 += 64){
    #pragma unroll
    for (int cc = tq; cc < 64; cc += 4)
      Tf[tn*65 + cc] = xb[(size_t)(c0+cc)*N_ + nb + tn];
    __syncthreads();
    #pragma unroll
    for (int nl = tq; nl < 64; nl += 4){
      int c = c0 + tn;
      Alds[nl][c ^ ((nl&7)<<3)] = f2bf(Tf[nl*65 + tn]);
    }
    __syncthreads();
  }
  int w = tid >> 6, l = tid & 63, lr = l & 15, lq = l >> 4;
  const unsigned short* W = (z==0) ? wqb : (z==1 ? wkb : wvb);
  const float* bias = (z==0) ? bq : (z==1 ? bk : bv);
  f32x4 zero = {0.f,0.f,0.f,0.f};
  f32x4 acc[16];
  #pragma unroll
  for (int i=0;i<16;i++) acc[i] = zero;
  #pragma unroll
  for (int ks = 0; ks < 8; ks++){
    s16x8 a = *(const s16x8*)&Alds[16*w + lr][(32*ks + 8*lq) ^ ((lr&7)<<3)];
    #pragma unroll
    for (int ct = 0; ct < 16; ct++){
      s16x8 bw = *(const s16x8*)&W[(size_t)(16*ct + lr)*C_ + 32*ks + 8*lq];
      acc[ct] = __builtin_amdgcn_mfma_f32_16x16x32_bf16(a, bw, acc[ct], 0, 0, 0);
    }
  }
  if (z < 2){
    unsigned short* ob = (z==0 ? Qn : Kn) + ((size_t)b*N_ + nb)*C_;
    #pragma unroll
    for (int ct = 0; ct < 16; ct++){
      int o = 16*ct + lr;
      float bi = bias[o];
      #pragma unroll
      for (int r = 0; r < 4; r++){
        int row = 16*w + 4*lq + r;
        ob[(size_t)row*C_ + o] = f2bf(acc[ct][r] + bi);
      }
    }
  } else {
    __syncthreads();
    #pragma unroll
    for (int ct = 0; ct < 16; ct++){
      int o = 16*ct + lr;
      float bi = bias[o];
      #pragma unroll
      for (int r = 0; r < 4; r++)
        Tlds[16*w + 4*lq + r][o] = f2bf(acc[ct][r] + bi);
    }
    __syncthreads();
    unsigned short* vb = Vc + (size_t)b*C_*N_;
    int j = tid & 63, o0 = tid >> 6;
    #pragma unroll
    for (int o = o0; o < 256; o += 4)
      vb[(size_t)o*N_ + nb + j] = Tlds[j][o];
  }
}

// ---------------- attention: 16x16 frags, 40KB LDS, 4 blocks/CU, NT beta ----
// grid 1024 x 256 thr = 4 blocks/CU (4 x 40960 = full pool). beta staged with
// CPol NT so the read-once stream is evict-first in L2 and the K/V working set
// (3MB/XCD incl. Q) stays resident -- fixes R16's 478MB HBM re-fetch thrash.
// Single beta buffer; per-wave P scratch aliases its own 2KB beta row-slice.
__global__ __launch_bounds__(256, 4) void k_attn(
    const unsigned short* __restrict__ Qn, const unsigned short* __restrict__ Kn,
    const unsigned short* __restrict__ Vc, const float* __restrict__ beta,
    unsigned short* __restrict__ Opb, float* __restrict__ Ls)
{
  __shared__ __align__(16) char smem[40960];
  unsigned short* Klds = (unsigned short*)smem;             // 16 KB [32 m][256 c]
  unsigned short* Vt   = (unsigned short*)(smem + 16384);   // 16 KB [256 c][32 m]
  float*          Bl   = (float*)(smem + 32768);            //  8 KB [64 q][32 m]
  const int tid = threadIdx.x;
  const int bid = blockIdx.x;
  const int b = bid & 7;
  const int jj = bid >> 3;                 // 0..127
  const int nt = jj & 31, mh = jj >> 5;    // nt 0..31, mh 0..3
  const int nb = nt*64;
  const unsigned short* Qb = Qn + (size_t)b*N_*C_;
  const unsigned short* Kb = Kn + (size_t)b*N_*C_;
  const unsigned short* Vb = Vc + (size_t)b*C_*N_;
  const float* betab = beta + (size_t)b*N_*N_;
  const int w = tid >> 6, lane = tid & 63, lr = lane & 15, lq = lane >> 4;
  const int wbase = (tid & ~63) * 16;
  // per-wave P scratch: aliases THIS wave's 16 beta rows (2KB each)
  unsigned short* Pw = (unsigned short*)((char*)Bl + w*2048);

  // Q A-frags: qf[ks] = Q[nb+16w+lr][32ks+8lq .. +8]  (regs whole kernel)
  s16x8 qf[8];
  {
    const unsigned short* qp = Qb + (size_t)(nb + 16*w + lr)*C_ + 8*lq;
    #pragma unroll
    for (int ks = 0; ks < 8; ks++)
      qf[ks] = *(const s16x8*)&qp[32*ks];
  }
  f32x4 zero = {0.f,0.f,0.f,0.f};
  f32x4 oacc[16];
  #pragma unroll
  for (int i=0;i<16;i++) oacc[i] = zero;
  float psum[4] = {0.f,0.f,0.f,0.f};

// K: LDS[row][slot16B] = K[mb+row][(slot^(row&31))*8 .. +8)  (32 rows x 32 slots)
#define STAGEK(MB) { \
  _Pragma("unroll") \
  for (int rr=0; rr<4; rr++){ \
    const int o_ = rr*4096 + tid*16; \
    const int row_ = o_ >> 9; \
    const int slot_ = (o_ >> 4) & 31; \
    gload_lds16(Kb + (size_t)((MB)+row_)*C_ + ((slot_ ^ (row_&31))<<3), \
                (char*)Klds + rr*4096 + wbase); } }
// V: LDS[c][slot16B] = V[c][(MB) + (slot^(c&3))*8 .. +8)   (256 c x 4 slots)
#define STAGEV(MB) { \
  _Pragma("unroll") \
  for (int rr=0; rr<4; rr++){ \
    const int o_ = rr*4096 + tid*16; \
    const int c_ = o_ >> 6; \
    const int slot_ = (o_ >> 4) & 3; \
    gload_lds16(Vb + (size_t)c_*N_ + (MB) + ((slot_ ^ (c_&3))<<3), \
                (char*)Vt + rr*4096 + wbase); } }
// beta: Bl[q][m] f32 linear, NT cache policy (streaming, evict-first)
#define STAGEB(MB) { \
  _Pragma("unroll") \
  for (int rr=0; rr<2; rr++){ \
    const int o_ = rr*4096 + tid*16; \
    const int row_ = o_ >> 7; \
    const int g_ = (o_ >> 4) & 7; \
    gload_lds16_nt(betab + (size_t)(nb+row_)*N_ + (MB) + g_*4, \
                   (char*)Bl + rr*4096 + wbase); } }

  // prologue: K(0), V(0), beta(0)
  STAGEK(mh*512)
  STAGEV(mh*512)
  STAGEB(mh*512)
  __syncthreads();

  for (int mt = 0; mt < 16; mt++){
    const int mb = mh*512 + mt*32;
    // beta(mt) from this wave's own rows of Bl
    f32x4 bv[2];
    #pragma unroll
    for (int ct=0; ct<2; ct++){
      #pragma unroll
      for (int r=0; r<4; r++)
        bv[ct][r] = Bl[(16*w + 4*lq + r)*32 + 16*ct + lr];
    }
    // S = Q K^T : S[q=16w+4lq+r][m=16ct+lr]
    f32x4 sacc[2];
    sacc[0] = zero; sacc[1] = zero;
    __builtin_amdgcn_s_setprio(1);
    #pragma unroll
    for (int ks=0; ks<8; ks++){
      #pragma unroll
      for (int ct=0; ct<2; ct++){
        const int row = 16*ct + lr;
        const s16x8 kf = *(const s16x8*)
            &Klds[row*256 + (((4*ks + lq) ^ (row&31)) << 3)];
        sacc[ct] = __builtin_amdgcn_mfma_f32_16x16x32_bf16(qf[ks], kf, sacc[ct], 0,0,0);
      }
    }
    __builtin_amdgcn_s_setprio(0);
    // P = exp(S*beta); psum partial; pack to per-wave scratch (own beta rows,
    // safe: this thread's bv reads precede these writes in program order)
    #pragma unroll
    for (int ct=0; ct<2; ct++)
      #pragma unroll
      for (int r=0; r<4; r++){
        float p = __expf(sacc[ct][r] * bv[ct][r]);
        psum[r] += p;
        Pw[(4*lq + r)*40 + 16*ct + lr] = f2bf(p);
      }
    // PV: O[q][c] += P[q][m] V[c][m]   (K=32, one MFMA per ct)
    {
      const s16x8 pf = *(const s16x8*)&Pw[lr*40 + 8*lq];
      __builtin_amdgcn_s_setprio(1);
      #pragma unroll
      for (int ct=0; ct<16; ct++){
        const int c = 16*ct + lr;
        const s16x8 vf = *(const s16x8*)
            &Vt[c*32 + ((lq ^ (c&3)) << 3)];
        oacc[ct] = __builtin_amdgcn_mfma_f32_16x16x32_bf16(pf, vf, oacc[ct], 0,0,0);
      }
      __builtin_amdgcn_s_setprio(0);
    }
    // barrier A: ALL waves' LDS reads (beta, K, V, P) for tile mt are done
    asm volatile("s_waitcnt lgkmcnt(0)" ::: "memory");
    __builtin_amdgcn_s_barrier();
    // stage next tile (K, V, beta) -- beta overwrites Bl incl. P scratch, safe
    if (mt + 1 < 16){
      STAGEK(mb + 32)
      STAGEV(mb + 32)
      STAGEB(mb + 32)
    }
    __syncthreads();   // drains all staging DMAs
  }
#undef STAGEK
#undef STAGEV
#undef STAGEB

  // psum reduce over the 16-lane lr group (lanes share (w,lq) -> same q rows)
  #pragma unroll
  for (int r=0;r<4;r++){
    #pragma unroll
    for (int d=1; d<16; d<<=1) psum[r] += __shfl_xor(psum[r], d, 64);
  }
  // store unnormalized bf16 partials
  unsigned short* Ob = Opb + ((size_t)mh*8 + b)*(size_t)N_*C_;
  #pragma unroll
  for (int ct=0; ct<16; ct++){
    const int c = 16*ct + lr;
    #pragma unroll
    for (int r=0; r<4; r++){
      const int qo = nb + 16*w + 4*lq + r;
      Ob[(size_t)qo*C_ + c] = f2bf(oacc[ct][r]);
    }
  }
  if (lr == 0){
    float* Lb = Ls + ((size_t)mh*8 + b)*N_;
    #pragma unroll
    for (int r=0;r<4;r++) Lb[nb + 16*w + 4*lq + r] = psum[r];
  }
}

// ---------------- fused MLP: merge+normalize -> conv1(BN,ReLU) -> conv2(BN,ReLU)
// -> conv3(+bias) -> residual add, all through LDS (overlaid phases).
__global__ __launch_bounds__(256) void k_mlpf(
    const unsigned short* __restrict__ Opb, const float* __restrict__ Ls,
    const unsigned short* __restrict__ W1, const float* __restrict__ sc1,
    const float* __restrict__ sh1,
    const unsigned short* __restrict__ W2, const float* __restrict__ sc2,
    const float* __restrict__ sh2,
    const unsigned short* __restrict__ W3, const float* __restrict__ b3,
    const float* __restrict__ x, float* __restrict__ out)
{
  __shared__ __align__(16) char smem[65792];
  unsigned short* Alds = (unsigned short*)smem;            // [64][256] @0 (phase1)
  unsigned short* H2   = (unsigned short*)(smem + 33024);  // [64][128]
  unsigned short* H1   = (unsigned short*)(smem + 49408);  // [64][128]
  float*          Dlds = (float*)smem;                     // [64][129] (phase3)
  int b = blockIdx.y, nt = blockIdx.x, nb = nt*64;
  int tid = threadIdx.x;
  const size_t PS = (size_t)8*N_*C_;
  for (int i = tid; i < 64*32; i += 256){
    int r = i >> 5, cv = i & 31;
    int row = nb + r;
    float ls = Ls[(size_t)b*N_ + row] + Ls[(size_t)(8+b)*N_ + row]
             + Ls[(size_t)(16+b)*N_ + row] + Ls[(size_t)(24+b)*N_ + row];
    float inv = 1.f / ls;
    size_t base = ((size_t)b*N_ + row)*C_ + cv*8;
    float a8[8] = {0.f,0.f,0.f,0.f,0.f,0.f,0.f,0.f};
    #pragma unroll
    for (int m=0;m<4;m++){
      s16x8 v = *(const s16x8*)&Opb[(size_t)m*PS + base];
      #pragma unroll
      for (int j=0;j<8;j++) a8[j] += bf2f((unsigned short)v[j]);
    }
    s16x8 o;
    #pragma unroll
    for (int j=0;j<8;j++) o[j] = (short)f2bf(a8[j] * inv);
    *(s16x8*)&Alds[r*256 + ((cv*8) ^ ((r&7)<<3))] = o;
  }
  __syncthreads();
  int w = tid >> 6, l = tid & 63, lr = l & 15, lq = l >> 4;
  f32x4 zero = {0.f,0.f,0.f,0.f};
  {
    f32x4 acc[8];
    #pragma unroll
    for (int i=0;i<8;i++) acc[i] = zero;
    #pragma unroll
    for (int ks = 0; ks < 8; ks++){
      s16x8 a = *(const s16x8*)&Alds[(16*w + lr)*256 + ((32*ks + 8*lq) ^ ((lr&7)<<3))];
      #pragma unroll
      for (int ct = 0; ct < 8; ct++){
        s16x8 bw = *(const s16x8*)&W1[(size_t)(16*ct + lr)*C_ + 32*ks + 8*lq];
        acc[ct] = __builtin_amdgcn_mfma_f32_16x16x32_bf16(a, bw, acc[ct], 0, 0, 0);
      }
    }
    __syncthreads();
    #pragma unroll
    for (int ct = 0; ct < 8; ct++){
      int o = 16*ct + lr;
      float s_ = sc1[o], h_ = sh1[o];
      #pragma unroll
      for (int r = 0; r < 4; r++){
        int row = 16*w + 4*lq + r;
        H1[row*128 + (o ^ ((row&7)<<3))] = f2bf(fmaxf(acc[ct][r]*s_ + h_, 0.f));
      }
    }
  }
  __syncthreads();
  {
    f32x4 acc[8];
    #pragma unroll
    for (int i=0;i<8;i++) acc[i] = zero;
    #pragma unroll
    for (int ks = 0; ks < 4; ks++){
      s16x8 a = *(const s16x8*)&H1[(16*w + lr)*128 + ((32*ks + 8*lq) ^ ((lr&7)<<3))];
      #pragma unroll
      for (int ct = 0; ct < 8; ct++){
        s16x8 bw = *(const s16x8*)&W2[(size_t)(16*ct + lr)*HC + 32*ks + 8*lq];
        acc[ct] = __builtin_amdgcn_mfma_f32_16x16x32_bf16(a, bw, acc[ct], 0, 0, 0);
      }
    }
    __syncthreads();
    #pragma unroll
    for (int ct = 0; ct < 8; ct++){
      int o = 16*ct + lr;
      float s_ = sc2[o], h_ = sh2[o];
      #pragma unroll
      for (int r = 0; r < 4; r++){
        int row = 16*w + 4*lq + r;
        H2[row*128 + (o ^ ((row&7)<<3))] = f2bf(fmaxf(acc[ct][r]*s_ + h_, 0.f));
      }
    }
  }
  __syncthreads();
  f32x4 acc[16];
  #pragma unroll
  for (int i=0;i<16;i++) acc[i] = zero;
  #pragma unroll
  for (int ks = 0; ks < 4; ks++){
    s16x8 a = *(const s16x8*)&H2[(16*w + lr)*128 + ((32*ks + 8*lq) ^ ((lr&7)<<3))];
    #pragma unroll
    for (int ct = 0; ct < 16; ct++){
      s16x8 bw = *(const s16x8*)&W3[(size_t)(16*ct + lr)*HC + 32*ks + 8*lq];
      acc[ct] = __builtin_amdgcn_mfma_f32_16x16x32_bf16(a, bw, acc[ct], 0, 0, 0);
    }
  }
  const float* xb = x + (size_t)b*C_*N_;
  float* ob = out + (size_t)b*C_*N_;
  int j = tid & 63, o0 = tid >> 6;
  #pragma unroll
  for (int half = 0; half < 2; half++){
    __syncthreads();
    #pragma unroll
    for (int ct = 8*half; ct < 8*half+8; ct++){
      int o = 16*ct + lr;
      float bi = b3[o];
      #pragma unroll
      for (int r = 0; r < 4; r++){
        int row = 16*w + 4*lq + r;
        Dlds[row*129 + (o - 128*half)] = acc[ct][r] + bi;
      }
    }
    __syncthreads();
    for (int o = 128*half + o0; o < 128*half + 128; o += 4)
      ob[(size_t)o*N_ + nb + j] = xb[(size_t)o*N_ + nb + j]
                                + Dlds[j*129 + (o - 128*half)];
  }
}

extern "C" void kernel_launch(void* const* d_in, const int* in_sizes, int n_in,
                              void* d_out, int out_size, void* d_ws, size_t ws_size,
                              hipStream_t stream)
{
  const float* x    = (const float*)d_in[0];
  const float* beta = (const float*)d_in[1];
  const float* wq = (const float*)d_in[2];  const float* bq = (const float*)d_in[3];
  const float* wk = (const float*)d_in[4];  const float* bk = (const float*)d_in[5];
  const float* wv = (const float*)d_in[6];  const float* bv = (const float*)d_in[7];
  const float* w1 = (const float*)d_in[8];  const float* b1 = (const float*)d_in[9];
  const float* g1 = (const float*)d_in[10]; const float* be1= (const float*)d_in[11];
  const float* m1 = (const float*)d_in[12]; const float* v1 = (const float*)d_in[13];
  const float* w2 = (const float*)d_in[14]; const float* b2 = (const float*)d_in[15];
  const float* g2 = (const float*)d_in[16]; const float* be2= (const float*)d_in[17];
  const float* m2 = (const float*)d_in[18]; const float* v2 = (const float*)d_in[19];
  const float* w3 = (const float*)d_in[20]; const float* b3 = (const float*)d_in[21];

  char* p = (char*)d_ws;
  auto alloc = [&](size_t n){ char* r = p; p += (n + 255) & ~(size_t)255; return r; };
  unsigned short* Qn  = (unsigned short*)alloc((size_t)B_*N_*C_*2);
  unsigned short* Kn  = (unsigned short*)alloc((size_t)B_*N_*C_*2);
  unsigned short* Vc  = (unsigned short*)alloc((size_t)B_*N_*C_*2);
  unsigned short* Opb = (unsigned short*)alloc((size_t)4*B_*N_*C_*2);
  float* Ls = (float*)alloc((size_t)4*B_*N_*4);
  unsigned short* wqb = (unsigned short*)alloc(65536*2);
  unsigned short* wkb = (unsigned short*)alloc(65536*2);
  unsigned short* wvb = (unsigned short*)alloc(65536*2);
  unsigned short* w1b = (unsigned short*)alloc(32768*2);
  unsigned short* w2b = (unsigned short*)alloc(16384*2);
  unsigned short* w3b = (unsigned short*)alloc(32768*2);
  float* sc1 = (float*)alloc(128*4);
  float* sh1 = (float*)alloc(128*4);
  float* sc2 = (float*)alloc(128*4);
  float* sh2 = (float*)alloc(128*4);

  PrepArgs pa;
  pa.s0 = wq; pa.s1 = wk; pa.s2 = wv; pa.s3 = w1; pa.s4 = w2; pa.s5 = w3;
  pa.d0 = wqb; pa.d1 = wkb; pa.d2 = wvb; pa.d3 = w1b; pa.d4 = w2b; pa.d5 = w3b;
  pa.b1 = b1; pa.g1 = g1; pa.be1 = be1; pa.m1 = m1; pa.v1 = v1;
  pa.b2 = b2; pa.g2 = g2; pa.be2 = be2; pa.m2 = m2; pa.v2 = v2;
  pa.sc1 = sc1; pa.sh1 = sh1; pa.sc2 = sc2; pa.sh2 = sh2;

  k_prep<<<dim3(1089), dim3(256), 0, stream>>>(pa);
  k_qkv<<<dim3(32, 8, 3), dim3(256), 0, stream>>>(x, wqb, wkb, wvb, bq, bk, bv, Qn, Kn, Vc);
  k_attn<<<dim3(1024), dim3(256), 0, stream>>>(Qn, Kn, Vc, beta, Opb, Ls);
  k_mlpf<<<dim3(32, 8), dim3(256), 0, stream>>>(Opb, Ls, w1b, sc1, sh1,
                                                w2b, sc2, sh2, w3b, b3,
                                                x, (float*)d_out);
}

// Round 18
// 177.911 us; speedup vs baseline: 1.8391x; 1.8145x over previous
//
#include <hip/hip_runtime.h>
#include <stdint.h>

#define B_ 8
#define C_ 256
#define N_ 2048
#define HC 128

typedef float f32x4 __attribute__((ext_vector_type(4)));
typedef short s16x8 __attribute__((ext_vector_type(8)));

__device__ __forceinline__ unsigned short f2bf(float f){
  union { float f; unsigned u; } v; v.f = f;
  unsigned r = v.u + 0x7FFF + ((v.u >> 16) & 1u);
  return (unsigned short)(r >> 16);
}
__device__ __forceinline__ float bf2f(unsigned short u){
  union { unsigned u; float f; } v; v.u = ((unsigned)u) << 16;
  return v.f;
}
__device__ __forceinline__ void gload_lds16(const void* g, void* l){
  __builtin_amdgcn_global_load_lds(
      (const __attribute__((address_space(1))) unsigned int*)g,
      (__attribute__((address_space(3))) unsigned int*)l, 16, 0, 0);
}

// ---------------- prep: weights -> bf16, BN affine fold ----------------
struct PrepArgs {
  const float *s0,*s1,*s2,*s3,*s4,*s5;
  unsigned short *d0,*d1,*d2,*d3,*d4,*d5;
  const float *b1,*g1,*be1,*m1,*v1;
  const float *b2,*g2,*be2,*m2,*v2;
  float *sc1,*sh1,*sc2,*sh2;
};

__global__ __launch_bounds__(256) void k_prep(PrepArgs a){
  int gid = blockIdx.x*256 + threadIdx.x;
  const int S0=65536, S1=131072, S2=196608, S3=229376, S4=245760, S5=278528;
  if (gid < S0)      a.d0[gid]    = f2bf(a.s0[gid]);
  else if (gid < S1) a.d1[gid-S0] = f2bf(a.s1[gid-S0]);
  else if (gid < S2) a.d2[gid-S1] = f2bf(a.s2[gid-S1]);
  else if (gid < S3) a.d3[gid-S2] = f2bf(a.s3[gid-S2]);
  else if (gid < S4) a.d4[gid-S3] = f2bf(a.s4[gid-S3]);
  else if (gid < S5) a.d5[gid-S4] = f2bf(a.s5[gid-S4]);
  else if (gid < S5+128){
    int o = gid - S5;
    float inv = a.g1[o] * rsqrtf(a.v1[o] + 1e-5f);
    a.sc1[o] = inv;
    a.sh1[o] = a.b1[o]*inv + a.be1[o] - a.m1[o]*inv;
  } else if (gid < S5+256){
    int o = gid - S5 - 128;
    float inv = a.g2[o] * rsqrtf(a.v2[o] + 1e-5f);
    a.sc2[o] = inv;
    a.sh2[o] = a.b2[o]*inv + a.be2[o] - a.m2[o]*inv;
  }
}

// ---------------- fused: x-transpose + QKV GEMM (z-split for parallelism) ----
__global__ __launch_bounds__(256) void k_qkv(
    const float* __restrict__ x,
    const unsigned short* __restrict__ wqb, const unsigned short* __restrict__ wkb,
    const unsigned short* __restrict__ wvb,
    const float* __restrict__ bq, const float* __restrict__ bk, const float* __restrict__ bv,
    unsigned short* __restrict__ Qn, unsigned short* __restrict__ Kn,
    unsigned short* __restrict__ Vc)
{
  __shared__ unsigned short Alds[64][256];
  __shared__ unsigned short Tlds[64][260];
  int b = blockIdx.y, nt = blockIdx.x, z = blockIdx.z;
  int nb = nt*64;
  const float* xb = x + (size_t)b*C_*N_;
  int tid = threadIdx.x;
  float* Tf = (float*)&Tlds[0][0];   // [64][65]
  int tn = tid & 63, tq = tid >> 6;
  for (int c0 = 0; c0 < 256; c0 += 64){
    #pragma unroll
    for (int cc = tq; cc < 64; cc += 4)
      Tf[tn*65 + cc] = xb[(size_t)(c0+cc)*N_ + nb + tn];
    __syncthreads();
    #pragma unroll
    for (int nl = tq; nl < 64; nl += 4){
      int c = c0 + tn;
      Alds[nl][c ^ ((nl&7)<<3)] = f2bf(Tf[nl*65 + tn]);
    }
    __syncthreads();
  }
  int w = tid >> 6, l = tid & 63, lr = l & 15, lq = l >> 4;
  const unsigned short* W = (z==0) ? wqb : (z==1 ? wkb : wvb);
  const float* bias = (z==0) ? bq : (z==1 ? bk : bv);
  f32x4 zero = {0.f,0.f,0.f,0.f};
  f32x4 acc[16];
  #pragma unroll
  for (int i=0;i<16;i++) acc[i] = zero;
  #pragma unroll
  for (int ks = 0; ks < 8; ks++){
    s16x8 a = *(const s16x8*)&Alds[16*w + lr][(32*ks + 8*lq) ^ ((lr&7)<<3)];
    #pragma unroll
    for (int ct = 0; ct < 16; ct++){
      s16x8 bw = *(const s16x8*)&W[(size_t)(16*ct + lr)*C_ + 32*ks + 8*lq];
      acc[ct] = __builtin_amdgcn_mfma_f32_16x16x32_bf16(a, bw, acc[ct], 0, 0, 0);
    }
  }
  if (z < 2){
    unsigned short* ob = (z==0 ? Qn : Kn) + ((size_t)b*N_ + nb)*C_;
    #pragma unroll
    for (int ct = 0; ct < 16; ct++){
      int o = 16*ct + lr;
      float bi = bias[o];
      #pragma unroll
      for (int r = 0; r < 4; r++){
        int row = 16*w + 4*lq + r;
        ob[(size_t)row*C_ + o] = f2bf(acc[ct][r] + bi);
      }
    }
  } else {
    __syncthreads();
    #pragma unroll
    for (int ct = 0; ct < 16; ct++){
      int o = 16*ct + lr;
      float bi = bias[o];
      #pragma unroll
      for (int r = 0; r < 4; r++)
        Tlds[16*w + 4*lq + r][o] = f2bf(acc[ct][r] + bi);
    }
    __syncthreads();
    unsigned short* vb = Vc + (size_t)b*C_*N_;
    int j = tid & 63, o0 = tid >> 6;
    #pragma unroll
    for (int o = o0; o < 256; o += 4)
      vb[(size_t)o*N_ + nb + j] = Tlds[j][o];
  }
}

// ---------------- attention: 16x16 frags, LDS padded to 52KB -> 3 blocks/CU ----
// grid 1024 x 256 thr. Actual LDS use = 40960B (K 16K + V 16K + beta/P 8K);
// declaration padded to 53248B (52KiB, 2KiB-granule exact) so the HW caps
// residency at EXACTLY 3 blocks/CU (3x53248=159744 <= 163840; 4x doesn't fit).
// Probes the thrash midpoint: 8 waves/CU = 90us clean, 16 waves = L2 thrash.
// Single beta buffer; per-wave P scratch aliases its own 2KB beta row-slice.
__global__ __launch_bounds__(256, 3) void k_attn(
    const unsigned short* __restrict__ Qn, const unsigned short* __restrict__ Kn,
    const unsigned short* __restrict__ Vc, const float* __restrict__ beta,
    unsigned short* __restrict__ Opb, float* __restrict__ Ls)
{
  __shared__ __align__(16) char smem[53248];
  unsigned short* Klds = (unsigned short*)smem;             // 16 KB [32 m][256 c]
  unsigned short* Vt   = (unsigned short*)(smem + 16384);   // 16 KB [256 c][32 m]
  float*          Bl   = (float*)(smem + 32768);            //  8 KB [64 q][32 m]
  const int tid = threadIdx.x;
  const int bid = blockIdx.x;
  const int b = bid & 7;
  const int jj = bid >> 3;                 // 0..127
  const int nt = jj & 31, mh = jj >> 5;    // nt 0..31, mh 0..3
  const int nb = nt*64;
  const unsigned short* Qb = Qn + (size_t)b*N_*C_;
  const unsigned short* Kb = Kn + (size_t)b*N_*C_;
  const unsigned short* Vb = Vc + (size_t)b*C_*N_;
  const float* betab = beta + (size_t)b*N_*N_;
  const int w = tid >> 6, lane = tid & 63, lr = lane & 15, lq = lane >> 4;
  const int wbase = (tid & ~63) * 16;
  // per-wave P scratch: aliases THIS wave's 16 beta rows (2KB each)
  unsigned short* Pw = (unsigned short*)((char*)Bl + w*2048);

  // Q A-frags: qf[ks] = Q[nb+16w+lr][32ks+8lq .. +8]  (regs whole kernel)
  s16x8 qf[8];
  {
    const unsigned short* qp = Qb + (size_t)(nb + 16*w + lr)*C_ + 8*lq;
    #pragma unroll
    for (int ks = 0; ks < 8; ks++)
      qf[ks] = *(const s16x8*)&qp[32*ks];
  }
  f32x4 zero = {0.f,0.f,0.f,0.f};
  f32x4 oacc[16];
  #pragma unroll
  for (int i=0;i<16;i++) oacc[i] = zero;
  float psum[4] = {0.f,0.f,0.f,0.f};

// K: LDS[row][slot16B] = K[mb+row][(slot^(row&31))*8 .. +8)  (32 rows x 32 slots)
#define STAGEK(MB) { \
  _Pragma("unroll") \
  for (int rr=0; rr<4; rr++){ \
    const int o_ = rr*4096 + tid*16; \
    const int row_ = o_ >> 9; \
    const int slot_ = (o_ >> 4) & 31; \
    gload_lds16(Kb + (size_t)((MB)+row_)*C_ + ((slot_ ^ (row_&31))<<3), \
                (char*)Klds + rr*4096 + wbase); } }
// V: LDS[c][slot16B] = V[c][(MB) + (slot^(c&3))*8 .. +8)   (256 c x 4 slots)
#define STAGEV(MB) { \
  _Pragma("unroll") \
  for (int rr=0; rr<4; rr++){ \
    const int o_ = rr*4096 + tid*16; \
    const int c_ = o_ >> 6; \
    const int slot_ = (o_ >> 4) & 3; \
    gload_lds16(Vb + (size_t)c_*N_ + (MB) + ((slot_ ^ (c_&3))<<3), \
                (char*)Vt + rr*4096 + wbase); } }
// beta: Bl[q][m] f32 linear
#define STAGEB(MB) { \
  _Pragma("unroll") \
  for (int rr=0; rr<2; rr++){ \
    const int o_ = rr*4096 + tid*16; \
    const int row_ = o_ >> 7; \
    const int g_ = (o_ >> 4) & 7; \
    gload_lds16(betab + (size_t)(nb+row_)*N_ + (MB) + g_*4, \
                (char*)Bl + rr*4096 + wbase); } }

  // prologue: K(0), V(0), beta(0)
  STAGEK(mh*512)
  STAGEV(mh*512)
  STAGEB(mh*512)
  __syncthreads();

  for (int mt = 0; mt < 16; mt++){
    const int mb = mh*512 + mt*32;
    // beta(mt) from this wave's own rows of Bl
    f32x4 bv[2];
    #pragma unroll
    for (int ct=0; ct<2; ct++){
      #pragma unroll
      for (int r=0; r<4; r++)
        bv[ct][r] = Bl[(16*w + 4*lq + r)*32 + 16*ct + lr];
    }
    // S = Q K^T : S[q=16w+4lq+r][m=16ct+lr]
    f32x4 sacc[2];
    sacc[0] = zero; sacc[1] = zero;
    __builtin_amdgcn_s_setprio(1);
    #pragma unroll
    for (int ks=0; ks<8; ks++){
      #pragma unroll
      for (int ct=0; ct<2; ct++){
        const int row = 16*ct + lr;
        const s16x8 kf = *(const s16x8*)
            &Klds[row*256 + (((4*ks + lq) ^ (row&31)) << 3)];
        sacc[ct] = __builtin_amdgcn_mfma_f32_16x16x32_bf16(qf[ks], kf, sacc[ct], 0,0,0);
      }
    }
    __builtin_amdgcn_s_setprio(0);
    // P = exp(S*beta); psum partial; pack to per-wave scratch (own beta rows,
    // safe: this thread's bv reads precede these writes in program order)
    #pragma unroll
    for (int ct=0; ct<2; ct++)
      #pragma unroll
      for (int r=0; r<4; r++){
        float p = __expf(sacc[ct][r] * bv[ct][r]);
        psum[r] += p;
        Pw[(4*lq + r)*40 + 16*ct + lr] = f2bf(p);
      }
    // PV: O[q][c] += P[q][m] V[c][m]   (K=32, one MFMA per ct)
    {
      const s16x8 pf = *(const s16x8*)&Pw[lr*40 + 8*lq];
      __builtin_amdgcn_s_setprio(1);
      #pragma unroll
      for (int ct=0; ct<16; ct++){
        const int c = 16*ct + lr;
        const s16x8 vf = *(const s16x8*)
            &Vt[c*32 + ((lq ^ (c&3)) << 3)];
        oacc[ct] = __builtin_amdgcn_mfma_f32_16x16x32_bf16(pf, vf, oacc[ct], 0,0,0);
      }
      __builtin_amdgcn_s_setprio(0);
    }
    // barrier A: ALL waves' LDS reads (beta, K, V, P) for tile mt are done
    asm volatile("s_waitcnt lgkmcnt(0)" ::: "memory");
    __builtin_amdgcn_s_barrier();
    // stage next tile (K, V, beta) -- beta overwrites Bl incl. P scratch, safe
    if (mt + 1 < 16){
      STAGEK(mb + 32)
      STAGEV(mb + 32)
      STAGEB(mb + 32)
    }
    __syncthreads();   // drains all staging DMAs
  }
#undef STAGEK
#undef STAGEV
#undef STAGEB

  // psum reduce over the 16-lane lr group (lanes share (w,lq) -> same q rows)
  #pragma unroll
  for (int r=0;r<4;r++){
    #pragma unroll
    for (int d=1; d<16; d<<=1) psum[r] += __shfl_xor(psum[r], d, 64);
  }
  // store unnormalized bf16 partials
  unsigned short* Ob = Opb + ((size_t)mh*8 + b)*(size_t)N_*C_;
  #pragma unroll
  for (int ct=0; ct<16; ct++){
    const int c = 16*ct + lr;
    #pragma unroll
    for (int r=0; r<4; r++){
      const int qo = nb + 16*w + 4*lq + r;
      Ob[(size_t)qo*C_ + c] = f2bf(oacc[ct][r]);
    }
  }
  if (lr == 0){
    float* Lb = Ls + ((size_t)mh*8 + b)*N_;
    #pragma unroll
    for (int r=0;r<4;r++) Lb[nb + 16*w + 4*lq + r] = psum[r];
  }
}

// ---------------- fused MLP: merge+normalize -> conv1(BN,ReLU) -> conv2(BN,ReLU)
// -> conv3(+bias) -> residual add, all through LDS (overlaid phases).
__global__ __launch_bounds__(256) void k_mlpf(
    const unsigned short* __restrict__ Opb, const float* __restrict__ Ls,
    const unsigned short* __restrict__ W1, const float* __restrict__ sc1,
    const float* __restrict__ sh1,
    const unsigned short* __restrict__ W2, const float* __restrict__ sc2,
    const float* __restrict__ sh2,
    const unsigned short* __restrict__ W3, const float* __restrict__ b3,
    const float* __restrict__ x, float* __restrict__ out)
{
  __shared__ __align__(16) char smem[65792];
  unsigned short* Alds = (unsigned short*)smem;            // [64][256] @0 (phase1)
  unsigned short* H2   = (unsigned short*)(smem + 33024);  // [64][128]
  unsigned short* H1   = (unsigned short*)(smem + 49408);  // [64][128]
  float*          Dlds = (float*)smem;                     // [64][129] (phase3)
  int b = blockIdx.y, nt = blockIdx.x, nb = nt*64;
  int tid = threadIdx.x;
  const size_t PS = (size_t)8*N_*C_;
  for (int i = tid; i < 64*32; i += 256){
    int r = i >> 5, cv = i & 31;
    int row = nb + r;
    float ls = Ls[(size_t)b*N_ + row] + Ls[(size_t)(8+b)*N_ + row]
             + Ls[(size_t)(16+b)*N_ + row] + Ls[(size_t)(24+b)*N_ + row];
    float inv = 1.f / ls;
    size_t base = ((size_t)b*N_ + row)*C_ + cv*8;
    float a8[8] = {0.f,0.f,0.f,0.f,0.f,0.f,0.f,0.f};
    #pragma unroll
    for (int m=0;m<4;m++){
      s16x8 v = *(const s16x8*)&Opb[(size_t)m*PS + base];
      #pragma unroll
      for (int j=0;j<8;j++) a8[j] += bf2f((unsigned short)v[j]);
    }
    s16x8 o;
    #pragma unroll
    for (int j=0;j<8;j++) o[j] = (short)f2bf(a8[j] * inv);
    *(s16x8*)&Alds[r*256 + ((cv*8) ^ ((r&7)<<3))] = o;
  }
  __syncthreads();
  int w = tid >> 6, l = tid & 63, lr = l & 15, lq = l >> 4;
  f32x4 zero = {0.f,0.f,0.f,0.f};
  {
    f32x4 acc[8];
    #pragma unroll
    for (int i=0;i<8;i++) acc[i] = zero;
    #pragma unroll
    for (int ks = 0; ks < 8; ks++){
      s16x8 a = *(const s16x8*)&Alds[(16*w + lr)*256 + ((32*ks + 8*lq) ^ ((lr&7)<<3))];
      #pragma unroll
      for (int ct = 0; ct < 8; ct++){
        s16x8 bw = *(const s16x8*)&W1[(size_t)(16*ct + lr)*C_ + 32*ks + 8*lq];
        acc[ct] = __builtin_amdgcn_mfma_f32_16x16x32_bf16(a, bw, acc[ct], 0, 0, 0);
      }
    }
    __syncthreads();
    #pragma unroll
    for (int ct = 0; ct < 8; ct++){
      int o = 16*ct + lr;
      float s_ = sc1[o], h_ = sh1[o];
      #pragma unroll
      for (int r = 0; r < 4; r++){
        int row = 16*w + 4*lq + r;
        H1[row*128 + (o ^ ((row&7)<<3))] = f2bf(fmaxf(acc[ct][r]*s_ + h_, 0.f));
      }
    }
  }
  __syncthreads();
  {
    f32x4 acc[8];
    #pragma unroll
    for (int i=0;i<8;i++) acc[i] = zero;
    #pragma unroll
    for (int ks = 0; ks < 4; ks++){
      s16x8 a = *(const s16x8*)&H1[(16*w + lr)*128 + ((32*ks + 8*lq) ^ ((lr&7)<<3))];
      #pragma unroll
      for (int ct = 0; ct < 8; ct++){
        s16x8 bw = *(const s16x8*)&W2[(size_t)(16*ct + lr)*HC + 32*ks + 8*lq];
        acc[ct] = __builtin_amdgcn_mfma_f32_16x16x32_bf16(a, bw, acc[ct], 0, 0, 0);
      }
    }
    __syncthreads();
    #pragma unroll
    for (int ct = 0; ct < 8; ct++){
      int o = 16*ct + lr;
      float s_ = sc2[o], h_ = sh2[o];
      #pragma unroll
      for (int r = 0; r < 4; r++){
        int row = 16*w + 4*lq + r;
        H2[row*128 + (o ^ ((row&7)<<3))] = f2bf(fmaxf(acc[ct][r]*s_ + h_, 0.f));
      }
    }
  }
  __syncthreads();
  f32x4 acc[16];
  #pragma unroll
  for (int i=0;i<16;i++) acc[i] = zero;
  #pragma unroll
  for (int ks = 0; ks < 4; ks++){
    s16x8 a = *(const s16x8*)&H2[(16*w + lr)*128 + ((32*ks + 8*lq) ^ ((lr&7)<<3))];
    #pragma unroll
    for (int ct = 0; ct < 16; ct++){
      s16x8 bw = *(const s16x8*)&W3[(size_t)(16*ct + lr)*HC + 32*ks + 8*lq];
      acc[ct] = __builtin_amdgcn_mfma_f32_16x16x32_bf16(a, bw, acc[ct], 0, 0, 0);
    }
  }
  const float* xb = x + (size_t)b*C_*N_;
  float* ob = out + (size_t)b*C_*N_;
  int j = tid & 63, o0 = tid >> 6;
  #pragma unroll
  for (int half = 0; half < 2; half++){
    __syncthreads();
    #pragma unroll
    for (int ct = 8*half; ct < 8*half+8; ct++){
      int o = 16*ct + lr;
      float bi = b3[o];
      #pragma unroll
      for (int r = 0; r < 4; r++){
        int row = 16*w + 4*lq + r;
        Dlds[row*129 + (o - 128*half)] = acc[ct][r] + bi;
      }
    }
    __syncthreads();
    for (int o = 128*half + o0; o < 128*half + 128; o += 4)
      ob[(size_t)o*N_ + nb + j] = xb[(size_t)o*N_ + nb + j]
                                + Dlds[j*129 + (o - 128*half)];
  }
}

extern "C" void kernel_launch(void* const* d_in, const int* in_sizes, int n_in,
                              void* d_out, int out_size, void* d_ws, size_t ws_size,
                              hipStream_t stream)
{
  const float* x    = (const float*)d_in[0];
  const float* beta = (const float*)d_in[1];
  const float* wq = (const float*)d_in[2];  const float* bq = (const float*)d_in[3];
  const float* wk = (const float*)d_in[4];  const float* bk = (const float*)d_in[5];
  const float* wv = (const float*)d_in[6];  const float* bv = (const float*)d_in[7];
  const float* w1 = (const float*)d_in[8];  const float* b1 = (const float*)d_in[9];
  const float* g1 = (const float*)d_in[10]; const float* be1= (const float*)d_in[11];
  const float* m1 = (const float*)d_in[12]; const float* v1 = (const float*)d_in[13];
  const float* w2 = (const float*)d_in[14]; const float* b2 = (const float*)d_in[15];
  const float* g2 = (const float*)d_in[16]; const float* be2= (const float*)d_in[17];
  const float* m2 = (const float*)d_in[18]; const float* v2 = (const float*)d_in[19];
  const float* w3 = (const float*)d_in[20]; const float* b3 = (const float*)d_in[21];

  char* p = (char*)d_ws;
  auto alloc = [&](size_t n){ char* r = p; p += (n + 255) & ~(size_t)255; return r; };
  unsigned short* Qn  = (unsigned short*)alloc((size_t)B_*N_*C_*2);
  unsigned short* Kn  = (unsigned short*)alloc((size_t)B_*N_*C_*2);
  unsigned short* Vc  = (unsigned short*)alloc((size_t)B_*N_*C_*2);
  unsigned short* Opb = (unsigned short*)alloc((size_t)4*B_*N_*C_*2);
  float* Ls = (float*)alloc((size_t)4*B_*N_*4);
  unsigned short* wqb = (unsigned short*)alloc(65536*2);
  unsigned short* wkb = (unsigned short*)alloc(65536*2);
  unsigned short* wvb = (unsigned short*)alloc(65536*2);
  unsigned short* w1b = (unsigned short*)alloc(32768*2);
  unsigned short* w2b = (unsigned short*)alloc(16384*2);
  unsigned short* w3b = (unsigned short*)alloc(32768*2);
  float* sc1 = (float*)alloc(128*4);
  float* sh1 = (float*)alloc(128*4);
  float* sc2 = (float*)alloc(128*4);
  float* sh2 = (float*)alloc(128*4);

  PrepArgs pa;
  pa.s0 = wq; pa.s1 = wk; pa.s2 = wv; pa.s3 = w1; pa.s4 = w2; pa.s5 = w3;
  pa.d0 = wqb; pa.d1 = wkb; pa.d2 = wvb; pa.d3 = w1b; pa.d4 = w2b; pa.d5 = w3b;
  pa.b1 = b1; pa.g1 = g1; pa.be1 = be1; pa.m1 = m1; pa.v1 = v1;
  pa.b2 = b2; pa.g2 = g2; pa.be2 = be2; pa.m2 = m2; pa.v2 = v2;
  pa.sc1 = sc1; pa.sh1 = sh1; pa.sc2 = sc2; pa.sh2 = sh2;

  k_prep<<<dim3(1089), dim3(256), 0, stream>>>(pa);
  k_qkv<<<dim3(32, 8, 3), dim3(256), 0, stream>>>(x, wqb, wkb, wvb, bq, bk, bv, Qn, Kn, Vc);
  k_attn<<<dim3(1024), dim3(256), 0, stream>>>(Qn, Kn, Vc, beta, Opb, Ls);
  k_mlpf<<<dim3(32, 8), dim3(256), 0, stream>>>(Opb, Ls, w1b, sc1, sh1,
                                                w2b, sc2, sh2, w3b, b3,
                                                x, (float*)d_out);
}

// Round 19
// 177.004 us; speedup vs baseline: 1.8485x; 1.0051x over previous
//
#include <hip/hip_runtime.h>
#include <stdint.h>

#define B_ 8
#define C_ 256
#define N_ 2048
#define HC 128

typedef float f32x4 __attribute__((ext_vector_type(4)));
typedef short s16x8 __attribute__((ext_vector_type(8)));

__device__ __forceinline__ unsigned short f2bf(float f){
  union { float f; unsigned u; } v; v.f = f;
  unsigned r = v.u + 0x7FFF + ((v.u >> 16) & 1u);
  return (unsigned short)(r >> 16);
}
__device__ __forceinline__ float bf2f(unsigned short u){
  union { unsigned u; float f; } v; v.u = ((unsigned)u) << 16;
  return v.f;
}
__device__ __forceinline__ void gload_lds16(const void* g, void* l){
  __builtin_amdgcn_global_load_lds(
      (const __attribute__((address_space(1))) unsigned int*)g,
      (__attribute__((address_space(3))) unsigned int*)l, 16, 0, 0);
}

// ---------------- prep: weights -> bf16, BN affine fold ----------------
struct PrepArgs {
  const float *s0,*s1,*s2,*s3,*s4,*s5;
  unsigned short *d0,*d1,*d2,*d3,*d4,*d5;
  const float *b1,*g1,*be1,*m1,*v1;
  const float *b2,*g2,*be2,*m2,*v2;
  float *sc1,*sh1,*sc2,*sh2;
};

__global__ __launch_bounds__(256) void k_prep(PrepArgs a){
  int gid = blockIdx.x*256 + threadIdx.x;
  const int S0=65536, S1=131072, S2=196608, S3=229376, S4=245760, S5=278528;
  if (gid < S0)      a.d0[gid]    = f2bf(a.s0[gid]);
  else if (gid < S1) a.d1[gid-S0] = f2bf(a.s1[gid-S0]);
  else if (gid < S2) a.d2[gid-S1] = f2bf(a.s2[gid-S1]);
  else if (gid < S3) a.d3[gid-S2] = f2bf(a.s3[gid-S2]);
  else if (gid < S4) a.d4[gid-S3] = f2bf(a.s4[gid-S3]);
  else if (gid < S5) a.d5[gid-S4] = f2bf(a.s5[gid-S4]);
  else if (gid < S5+128){
    int o = gid - S5;
    float inv = a.g1[o] * rsqrtf(a.v1[o] + 1e-5f);
    a.sc1[o] = inv;
    a.sh1[o] = a.b1[o]*inv + a.be1[o] - a.m1[o]*inv;
  } else if (gid < S5+256){
    int o = gid - S5 - 128;
    float inv = a.g2[o] * rsqrtf(a.v2[o] + 1e-5f);
    a.sc2[o] = inv;
    a.sh2[o] = a.b2[o]*inv + a.be2[o] - a.m2[o]*inv;
  }
}

// ---------------- fused: x-transpose + QKV GEMM (z-split for parallelism) ----
__global__ __launch_bounds__(256) void k_qkv(
    const float* __restrict__ x,
    const unsigned short* __restrict__ wqb, const unsigned short* __restrict__ wkb,
    const unsigned short* __restrict__ wvb,
    const float* __restrict__ bq, const float* __restrict__ bk, const float* __restrict__ bv,
    unsigned short* __restrict__ Qn, unsigned short* __restrict__ Kn,
    unsigned short* __restrict__ Vc)
{
  __shared__ unsigned short Alds[64][256];
  __shared__ unsigned short Tlds[64][260];
  int b = blockIdx.y, nt = blockIdx.x, z = blockIdx.z;
  int nb = nt*64;
  const float* xb = x + (size_t)b*C_*N_;
  int tid = threadIdx.x;
  float* Tf = (float*)&Tlds[0][0];   // [64][65]
  int tn = tid & 63, tq = tid >> 6;
  for (int c0 = 0; c0 < 256; c0 += 64){
    #pragma unroll
    for (int cc = tq; cc < 64; cc += 4)
      Tf[tn*65 + cc] = xb[(size_t)(c0+cc)*N_ + nb + tn];
    __syncthreads();
    #pragma unroll
    for (int nl = tq; nl < 64; nl += 4){
      int c = c0 + tn;
      Alds[nl][c ^ ((nl&7)<<3)] = f2bf(Tf[nl*65 + tn]);
    }
    __syncthreads();
  }
  int w = tid >> 6, l = tid & 63, lr = l & 15, lq = l >> 4;
  const unsigned short* W = (z==0) ? wqb : (z==1 ? wkb : wvb);
  const float* bias = (z==0) ? bq : (z==1 ? bk : bv);
  f32x4 zero = {0.f,0.f,0.f,0.f};
  f32x4 acc[16];
  #pragma unroll
  for (int i=0;i<16;i++) acc[i] = zero;
  #pragma unroll
  for (int ks = 0; ks < 8; ks++){
    s16x8 a = *(const s16x8*)&Alds[16*w + lr][(32*ks + 8*lq) ^ ((lr&7)<<3)];
    #pragma unroll
    for (int ct = 0; ct < 16; ct++){
      s16x8 bw = *(const s16x8*)&W[(size_t)(16*ct + lr)*C_ + 32*ks + 8*lq];
      acc[ct] = __builtin_amdgcn_mfma_f32_16x16x32_bf16(a, bw, acc[ct], 0, 0, 0);
    }
  }
  if (z < 2){
    unsigned short* ob = (z==0 ? Qn : Kn) + ((size_t)b*N_ + nb)*C_;
    #pragma unroll
    for (int ct = 0; ct < 16; ct++){
      int o = 16*ct + lr;
      float bi = bias[o];
      #pragma unroll
      for (int r = 0; r < 4; r++){
        int row = 16*w + 4*lq + r;
        ob[(size_t)row*C_ + o] = f2bf(acc[ct][r] + bi);
      }
    }
  } else {
    __syncthreads();
    #pragma unroll
    for (int ct = 0; ct < 16; ct++){
      int o = 16*ct + lr;
      float bi = bias[o];
      #pragma unroll
      for (int r = 0; r < 4; r++)
        Tlds[16*w + 4*lq + r][o] = f2bf(acc[ct][r] + bi);
    }
    __syncthreads();
    unsigned short* vb = Vc + (size_t)b*C_*N_;
    int j = tid & 63, o0 = tid >> 6;
    #pragma unroll
    for (int o = o0; o < 256; o += 4)
      vb[(size_t)o*N_ + nb + j] = Tlds[j][o];
  }
}

// ---------------- attention: 16x16 frags, 48KB LDS -> 3 blocks/CU, beta dbuf ----
// grid 1024 x 256 thr. LDS = K 16K + V 16K + beta dbuf 2x8K = 49152 B exactly
// (multiple of the 8KiB allocation granule measured in R14..R18); 3x49152 =
// 147456 <= 163840 -> 3 blocks/CU, 4x doesn't fit. Beta double-buffered and
// issued at TOP of compute (R15's proven schedule, 90us at 2 blocks); P scratch
// aliases each wave's own 2KB row-slice of the CURRENT beta buffer (written
// after that wave's beta reads; overwritten by DMA only after the next
// bottom-sync -- hazard chain validated in R16/R18 passing runs).
__global__ __launch_bounds__(256, 3) void k_attn(
    const unsigned short* __restrict__ Qn, const unsigned short* __restrict__ Kn,
    const unsigned short* __restrict__ Vc, const float* __restrict__ beta,
    unsigned short* __restrict__ Opb, float* __restrict__ Ls)
{
  __shared__ __align__(16) char smem[49152];
  unsigned short* Klds = (unsigned short*)smem;             // 16 KB [32 m][256 c]
  unsigned short* Vt   = (unsigned short*)(smem + 16384);   // 16 KB [256 c][32 m]
  float*          Bl   = (float*)(smem + 32768);            // 2x8KB [64 q][32 m]
  const int tid = threadIdx.x;
  const int bid = blockIdx.x;
  const int b = bid & 7;
  const int jj = bid >> 3;                 // 0..127
  const int nt = jj & 31, mh = jj >> 5;    // nt 0..31, mh 0..3
  const int nb = nt*64;
  const unsigned short* Qb = Qn + (size_t)b*N_*C_;
  const unsigned short* Kb = Kn + (size_t)b*N_*C_;
  const unsigned short* Vb = Vc + (size_t)b*C_*N_;
  const float* betab = beta + (size_t)b*N_*N_;
  const int w = tid >> 6, lane = tid & 63, lr = lane & 15, lq = lane >> 4;
  const int wbase = (tid & ~63) * 16;

  // Q A-frags: qf[ks] = Q[nb+16w+lr][32ks+8lq .. +8]  (regs whole kernel)
  s16x8 qf[8];
  {
    const unsigned short* qp = Qb + (size_t)(nb + 16*w + lr)*C_ + 8*lq;
    #pragma unroll
    for (int ks = 0; ks < 8; ks++)
      qf[ks] = *(const s16x8*)&qp[32*ks];
  }
  f32x4 zero = {0.f,0.f,0.f,0.f};
  f32x4 oacc[16];
  #pragma unroll
  for (int i=0;i<16;i++) oacc[i] = zero;
  float psum[4] = {0.f,0.f,0.f,0.f};

// K: LDS[row][slot16B] = K[mb+row][(slot^(row&31))*8 .. +8)  (32 rows x 32 slots)
#define STAGEK(MB) { \
  _Pragma("unroll") \
  for (int rr=0; rr<4; rr++){ \
    const int o_ = rr*4096 + tid*16; \
    const int row_ = o_ >> 9; \
    const int slot_ = (o_ >> 4) & 31; \
    gload_lds16(Kb + (size_t)((MB)+row_)*C_ + ((slot_ ^ (row_&31))<<3), \
                (char*)Klds + rr*4096 + wbase); } }
// V: LDS[c][slot16B] = V[c][(MB) + (slot^(c&3))*8 .. +8)   (256 c x 4 slots)
#define STAGEV(MB) { \
  _Pragma("unroll") \
  for (int rr=0; rr<4; rr++){ \
    const int o_ = rr*4096 + tid*16; \
    const int c_ = o_ >> 6; \
    const int slot_ = (o_ >> 4) & 3; \
    gload_lds16(Vb + (size_t)c_*N_ + (MB) + ((slot_ ^ (c_&3))<<3), \
                (char*)Vt + rr*4096 + wbase); } }
// beta: buf[q][m] f32 linear   (64 q x 32 m = 8KB per buffer)
#define STAGEB(BUF, MB) { \
  _Pragma("unroll") \
  for (int rr=0; rr<2; rr++){ \
    const int o_ = rr*4096 + tid*16; \
    const int row_ = o_ >> 7; \
    const int g_ = (o_ >> 4) & 7; \
    gload_lds16(betab + (size_t)(nb+row_)*N_ + (MB) + g_*4, \
                (char*)Bl + (BUF)*8192 + rr*4096 + wbase); } }

  // prologue: K(0), V(0), beta(0)
  STAGEK(mh*512)
  STAGEV(mh*512)
  STAGEB(0, mh*512)
  __syncthreads();

  for (int mt = 0; mt < 16; mt++){
    const int mb = mh*512 + mt*32;
    // issue NEXT tile's beta into the other buffer (flies under compute)
    if (mt + 1 < 16){
      STAGEB((mt+1)&1, mb+32)
    }
    const float* Bp = Bl + (mt&1)*2048;   // current beta buffer (floats)
    // per-wave P scratch aliases THIS wave's 2KB row-slice of current buffer
    unsigned short* Pw = (unsigned short*)((char*)Bl + (mt&1)*8192 + w*2048);
    // beta(mt): this wave's own rows
    f32x4 bv[2];
    #pragma unroll
    for (int ct=0; ct<2; ct++){
      #pragma unroll
      for (int r=0; r<4; r++)
        bv[ct][r] = Bp[(16*w + 4*lq + r)*32 + 16*ct + lr];
    }
    // S = Q K^T : S[q=16w+4lq+r][m=16ct+lr]
    f32x4 sacc[2];
    sacc[0] = zero; sacc[1] = zero;
    __builtin_amdgcn_s_setprio(1);
    #pragma unroll
    for (int ks=0; ks<8; ks++){
      #pragma unroll
      for (int ct=0; ct<2; ct++){
        const int row = 16*ct + lr;
        const s16x8 kf = *(const s16x8*)
            &Klds[row*256 + (((4*ks + lq) ^ (row&31)) << 3)];
        sacc[ct] = __builtin_amdgcn_mfma_f32_16x16x32_bf16(qf[ks], kf, sacc[ct], 0,0,0);
      }
    }
    __builtin_amdgcn_s_setprio(0);
    // P = exp(S*beta); psum partial; pack to per-wave scratch (own beta rows,
    // safe: this thread's bv reads precede these writes in program order)
    #pragma unroll
    for (int ct=0; ct<2; ct++)
      #pragma unroll
      for (int r=0; r<4; r++){
        float p = __expf(sacc[ct][r] * bv[ct][r]);
        psum[r] += p;
        Pw[(4*lq + r)*40 + 16*ct + lr] = f2bf(p);
      }
    // PV: O[q][c] += P[q][m] V[c][m]   (K=32, one MFMA per ct)
    {
      const s16x8 pf = *(const s16x8*)&Pw[lr*40 + 8*lq];
      __builtin_amdgcn_s_setprio(1);
      #pragma unroll
      for (int ct=0; ct<16; ct++){
        const int c = 16*ct + lr;
        const s16x8 vf = *(const s16x8*)
            &Vt[c*32 + ((lq ^ (c&3)) << 3)];
        oacc[ct] = __builtin_amdgcn_mfma_f32_16x16x32_bf16(pf, vf, oacc[ct], 0,0,0);
      }
      __builtin_amdgcn_s_setprio(0);
    }
    // barrier A: all waves' LDS reads for tile mt done (VMEM queue untouched)
    asm volatile("s_waitcnt lgkmcnt(0)" ::: "memory");
    __builtin_amdgcn_s_barrier();
    if (mt + 1 < 16){
      STAGEK(mb + 32)
      STAGEV(mb + 32)
    }
    __syncthreads();   // drains K/V staging + the already-flown beta(t+1)
  }
#undef STAGEK
#undef STAGEV
#undef STAGEB

  // psum reduce over the 16-lane lr group (lanes share (w,lq) -> same q rows)
  #pragma unroll
  for (int r=0;r<4;r++){
    #pragma unroll
    for (int d=1; d<16; d<<=1) psum[r] += __shfl_xor(psum[r], d, 64);
  }
  // store unnormalized bf16 partials
  unsigned short* Ob = Opb + ((size_t)mh*8 + b)*(size_t)N_*C_;
  #pragma unroll
  for (int ct=0; ct<16; ct++){
    const int c = 16*ct + lr;
    #pragma unroll
    for (int r=0; r<4; r++){
      const int qo = nb + 16*w + 4*lq + r;
      Ob[(size_t)qo*C_ + c] = f2bf(oacc[ct][r]);
    }
  }
  if (lr == 0){
    float* Lb = Ls + ((size_t)mh*8 + b)*N_;
    #pragma unroll
    for (int r=0;r<4;r++) Lb[nb + 16*w + 4*lq + r] = psum[r];
  }
}

// ---------------- fused MLP: merge+normalize -> conv1(BN,ReLU) -> conv2(BN,ReLU)
// -> conv3(+bias) -> residual add, all through LDS (overlaid phases).
__global__ __launch_bounds__(256) void k_mlpf(
    const unsigned short* __restrict__ Opb, const float* __restrict__ Ls,
    const unsigned short* __restrict__ W1, const float* __restrict__ sc1,
    const float* __restrict__ sh1,
    const unsigned short* __restrict__ W2, const float* __restrict__ sc2,
    const float* __restrict__ sh2,
    const unsigned short* __restrict__ W3, const float* __restrict__ b3,
    const float* __restrict__ x, float* __restrict__ out)
{
  __shared__ __align__(16) char smem[65792];
  unsigned short* Alds = (unsigned short*)smem;            // [64][256] @0 (phase1)
  unsigned short* H2   = (unsigned short*)(smem + 33024);  // [64][128]
  unsigned short* H1   = (unsigned short*)(smem + 49408);  // [64][128]
  float*          Dlds = (float*)smem;                     // [64][129] (phase3)
  int b = blockIdx.y, nt = blockIdx.x, nb = nt*64;
  int tid = threadIdx.x;
  const size_t PS = (size_t)8*N_*C_;
  for (int i = tid; i < 64*32; i += 256){
    int r = i >> 5, cv = i & 31;
    int row = nb + r;
    float ls = Ls[(size_t)b*N_ + row] + Ls[(size_t)(8+b)*N_ + row]
             + Ls[(size_t)(16+b)*N_ + row] + Ls[(size_t)(24+b)*N_ + row];
    float inv = 1.f / ls;
    size_t base = ((size_t)b*N_ + row)*C_ + cv*8;
    float a8[8] = {0.f,0.f,0.f,0.f,0.f,0.f,0.f,0.f};
    #pragma unroll
    for (int m=0;m<4;m++){
      s16x8 v = *(const s16x8*)&Opb[(size_t)m*PS + base];
      #pragma unroll
      for (int j=0;j<8;j++) a8[j] += bf2f((unsigned short)v[j]);
    }
    s16x8 o;
    #pragma unroll
    for (int j=0;j<8;j++) o[j] = (short)f2bf(a8[j] * inv);
    *(s16x8*)&Alds[r*256 + ((cv*8) ^ ((r&7)<<3))] = o;
  }
  __syncthreads();
  int w = tid >> 6, l = tid & 63, lr = l & 15, lq = l >> 4;
  f32x4 zero = {0.f,0.f,0.f,0.f};
  {
    f32x4 acc[8];
    #pragma unroll
    for (int i=0;i<8;i++) acc[i] = zero;
    #pragma unroll
    for (int ks = 0; ks < 8; ks++){
      s16x8 a = *(const s16x8*)&Alds[(16*w + lr)*256 + ((32*ks + 8*lq) ^ ((lr&7)<<3))];
      #pragma unroll
      for (int ct = 0; ct < 8; ct++){
        s16x8 bw = *(const s16x8*)&W1[(size_t)(16*ct + lr)*C_ + 32*ks + 8*lq];
        acc[ct] = __builtin_amdgcn_mfma_f32_16x16x32_bf16(a, bw, acc[ct], 0, 0, 0);
      }
    }
    __syncthreads();
    #pragma unroll
    for (int ct = 0; ct < 8; ct++){
      int o = 16*ct + lr;
      float s_ = sc1[o], h_ = sh1[o];
      #pragma unroll
      for (int r = 0; r < 4; r++){
        int row = 16*w + 4*lq + r;
        H1[row*128 + (o ^ ((row&7)<<3))] = f2bf(fmaxf(acc[ct][r]*s_ + h_, 0.f));
      }
    }
  }
  __syncthreads();
  {
    f32x4 acc[8];
    #pragma unroll
    for (int i=0;i<8;i++) acc[i] = zero;
    #pragma unroll
    for (int ks = 0; ks < 4; ks++){
      s16x8 a = *(const s16x8*)&H1[(16*w + lr)*128 + ((32*ks + 8*lq) ^ ((lr&7)<<3))];
      #pragma unroll
      for (int ct = 0; ct < 8; ct++){
        s16x8 bw = *(const s16x8*)&W2[(size_t)(16*ct + lr)*HC + 32*ks + 8*lq];
        acc[ct] = __builtin_amdgcn_mfma_f32_16x16x32_bf16(a, bw, acc[ct], 0, 0, 0);
      }
    }
    __syncthreads();
    #pragma unroll
    for (int ct = 0; ct < 8; ct++){
      int o = 16*ct + lr;
      float s_ = sc2[o], h_ = sh2[o];
      #pragma unroll
      for (int r = 0; r < 4; r++){
        int row = 16*w + 4*lq + r;
        H2[row*128 + (o ^ ((row&7)<<3))] = f2bf(fmaxf(acc[ct][r]*s_ + h_, 0.f));
      }
    }
  }
  __syncthreads();
  f32x4 acc[16];
  #pragma unroll
  for (int i=0;i<16;i++) acc[i] = zero;
  #pragma unroll
  for (int ks = 0; ks < 4; ks++){
    s16x8 a = *(const s16x8*)&H2[(16*w + lr)*128 + ((32*ks + 8*lq) ^ ((lr&7)<<3))];
    #pragma unroll
    for (int ct = 0; ct < 16; ct++){
      s16x8 bw = *(const s16x8*)&W3[(size_t)(16*ct + lr)*HC + 32*ks + 8*lq];
      acc[ct] = __builtin_amdgcn_mfma_f32_16x16x32_bf16(a, bw, acc[ct], 0, 0, 0);
    }
  }
  const float* xb = x + (size_t)b*C_*N_;
  float* ob = out + (size_t)b*C_*N_;
  int j = tid & 63, o0 = tid >> 6;
  #pragma unroll
  for (int half = 0; half < 2; half++){
    __syncthreads();
    #pragma unroll
    for (int ct = 8*half; ct < 8*half+8; ct++){
      int o = 16*ct + lr;
      float bi = b3[o];
      #pragma unroll
      for (int r = 0; r < 4; r++){
        int row = 16*w + 4*lq + r;
        Dlds[row*129 + (o - 128*half)] = acc[ct][r] + bi;
      }
    }
    __syncthreads();
    for (int o = 128*half + o0; o < 128*half + 128; o += 4)
      ob[(size_t)o*N_ + nb + j] = xb[(size_t)o*N_ + nb + j]
                                + Dlds[j*129 + (o - 128*half)];
  }
}

extern "C" void kernel_launch(void* const* d_in, const int* in_sizes, int n_in,
                              void* d_out, int out_size, void* d_ws, size_t ws_size,
                              hipStream_t stream)
{
  const float* x    = (const float*)d_in[0];
  const float* beta = (const float*)d_in[1];
  const float* wq = (const float*)d_in[2];  const float* bq = (const float*)d_in[3];
  const float* wk = (const float*)d_in[4];  const float* bk = (const float*)d_in[5];
  const float* wv = (const float*)d_in[6];  const float* bv = (const float*)d_in[7];
  const float* w1 = (const float*)d_in[8];  const float* b1 = (const float*)d_in[9];
  const float* g1 = (const float*)d_in[10]; const float* be1= (const float*)d_in[11];
  const float* m1 = (const float*)d_in[12]; const float* v1 = (const float*)d_in[13];
  const float* w2 = (const float*)d_in[14]; const float* b2 = (const float*)d_in[15];
  const float* g2 = (const float*)d_in[16]; const float* be2= (const float*)d_in[17];
  const float* m2 = (const float*)d_in[18]; const float* v2 = (const float*)d_in[19];
  const float* w3 = (const float*)d_in[20]; const float* b3 = (const float*)d_in[21];

  char* p = (char*)d_ws;
  auto alloc = [&](size_t n){ char* r = p; p += (n + 255) & ~(size_t)255; return r; };
  unsigned short* Qn  = (unsigned short*)alloc((size_t)B_*N_*C_*2);
  unsigned short* Kn  = (unsigned short*)alloc((size_t)B_*N_*C_*2);
  unsigned short* Vc  = (unsigned short*)alloc((size_t)B_*N_*C_*2);
  unsigned short* Opb = (unsigned short*)alloc((size_t)4*B_*N_*C_*2);
  float* Ls = (float*)alloc((size_t)4*B_*N_*4);
  unsigned short* wqb = (unsigned short*)alloc(65536*2);
  unsigned short* wkb = (unsigned short*)alloc(65536*2);
  unsigned short* wvb = (unsigned short*)alloc(65536*2);
  unsigned short* w1b = (unsigned short*)alloc(32768*2);
  unsigned short* w2b = (unsigned short*)alloc(16384*2);
  unsigned short* w3b = (unsigned short*)alloc(32768*2);
  float* sc1 = (float*)alloc(128*4);
  float* sh1 = (float*)alloc(128*4);
  float* sc2 = (float*)alloc(128*4);
  float* sh2 = (float*)alloc(128*4);

  PrepArgs pa;
  pa.s0 = wq; pa.s1 = wk; pa.s2 = wv; pa.s3 = w1; pa.s4 = w2; pa.s5 = w3;
  pa.d0 = wqb; pa.d1 = wkb; pa.d2 = wvb; pa.d3 = w1b; pa.d4 = w2b; pa.d5 = w3b;
  pa.b1 = b1; pa.g1 = g1; pa.be1 = be1; pa.m1 = m1; pa.v1 = v1;
  pa.b2 = b2; pa.g2 = g2; pa.be2 = be2; pa.m2 = m2; pa.v2 = v2;
  pa.sc1 = sc1; pa.sh1 = sh1; pa.sc2 = sc2; pa.sh2 = sh2;

  k_prep<<<dim3(1089), dim3(256), 0, stream>>>(pa);
  k_qkv<<<dim3(32, 8, 3), dim3(256), 0, stream>>>(x, wqb, wkb, wvb, bq, bk, bv, Qn, Kn, Vc);
  k_attn<<<dim3(1024), dim3(256), 0, stream>>>(Qn, Kn, Vc, beta, Opb, Ls);
  k_mlpf<<<dim3(32, 8), dim3(256), 0, stream>>>(Opb, Ls, w1b, sc1, sh1,
                                                w2b, sc2, sh2, w3b, b3,
                                                x, (float*)d_out);
}

// Round 20
// 176.903 us; speedup vs baseline: 1.8495x; 1.0006x over previous
//
#include <hip/hip_runtime.h>
#include <stdint.h>

#define B_ 8
#define C_ 256
#define N_ 2048
#define HC 128

typedef float f32x4 __attribute__((ext_vector_type(4)));
typedef short s16x8 __attribute__((ext_vector_type(8)));

__device__ __forceinline__ unsigned short f2bf(float f){
  union { float f; unsigned u; } v; v.f = f;
  unsigned r = v.u + 0x7FFF + ((v.u >> 16) & 1u);
  return (unsigned short)(r >> 16);
}
__device__ __forceinline__ float bf2f(unsigned short u){
  union { unsigned u; float f; } v; v.u = ((unsigned)u) << 16;
  return v.f;
}
__device__ __forceinline__ void gload_lds16(const void* g, void* l){
  __builtin_amdgcn_global_load_lds(
      (const __attribute__((address_space(1))) unsigned int*)g,
      (__attribute__((address_space(3))) unsigned int*)l, 16, 0, 0);
}

// ---------------- prep: weights -> bf16, BN affine fold ----------------
struct PrepArgs {
  const float *s0,*s1,*s2,*s3,*s4,*s5;
  unsigned short *d0,*d1,*d2,*d3,*d4,*d5;
  const float *b1,*g1,*be1,*m1,*v1;
  const float *b2,*g2,*be2,*m2,*v2;
  float *sc1,*sh1,*sc2,*sh2;
};

__global__ __launch_bounds__(256) void k_prep(PrepArgs a){
  int gid = blockIdx.x*256 + threadIdx.x;
  const int S0=65536, S1=131072, S2=196608, S3=229376, S4=245760, S5=278528;
  if (gid < S0)      a.d0[gid]    = f2bf(a.s0[gid]);
  else if (gid < S1) a.d1[gid-S0] = f2bf(a.s1[gid-S0]);
  else if (gid < S2) a.d2[gid-S1] = f2bf(a.s2[gid-S1]);
  else if (gid < S3) a.d3[gid-S2] = f2bf(a.s3[gid-S2]);
  else if (gid < S4) a.d4[gid-S3] = f2bf(a.s4[gid-S3]);
  else if (gid < S5) a.d5[gid-S4] = f2bf(a.s5[gid-S4]);
  else if (gid < S5+128){
    int o = gid - S5;
    float inv = a.g1[o] * rsqrtf(a.v1[o] + 1e-5f);
    a.sc1[o] = inv;
    a.sh1[o] = a.b1[o]*inv + a.be1[o] - a.m1[o]*inv;
  } else if (gid < S5+256){
    int o = gid - S5 - 128;
    float inv = a.g2[o] * rsqrtf(a.v2[o] + 1e-5f);
    a.sc2[o] = inv;
    a.sh2[o] = a.b2[o]*inv + a.be2[o] - a.m2[o]*inv;
  }
}

// ---------------- fused: x-transpose + QKV GEMM (z-split for parallelism) ----
__global__ __launch_bounds__(256) void k_qkv(
    const float* __restrict__ x,
    const unsigned short* __restrict__ wqb, const unsigned short* __restrict__ wkb,
    const unsigned short* __restrict__ wvb,
    const float* __restrict__ bq, const float* __restrict__ bk, const float* __restrict__ bv,
    unsigned short* __restrict__ Qn, unsigned short* __restrict__ Kn,
    unsigned short* __restrict__ Vc)
{
  __shared__ unsigned short Alds[64][256];
  __shared__ unsigned short Tlds[64][260];
  int b = blockIdx.y, nt = blockIdx.x, z = blockIdx.z;
  int nb = nt*64;
  const float* xb = x + (size_t)b*C_*N_;
  int tid = threadIdx.x;
  float* Tf = (float*)&Tlds[0][0];   // [64][65]
  int tn = tid & 63, tq = tid >> 6;
  for (int c0 = 0; c0 < 256; c0 += 64){
    #pragma unroll
    for (int cc = tq; cc < 64; cc += 4)
      Tf[tn*65 + cc] = xb[(size_t)(c0+cc)*N_ + nb + tn];
    __syncthreads();
    #pragma unroll
    for (int nl = tq; nl < 64; nl += 4){
      int c = c0 + tn;
      Alds[nl][c ^ ((nl&7)<<3)] = f2bf(Tf[nl*65 + tn]);
    }
    __syncthreads();
  }
  int w = tid >> 6, l = tid & 63, lr = l & 15, lq = l >> 4;
  const unsigned short* W = (z==0) ? wqb : (z==1 ? wkb : wvb);
  const float* bias = (z==0) ? bq : (z==1 ? bk : bv);
  f32x4 zero = {0.f,0.f,0.f,0.f};
  f32x4 acc[16];
  #pragma unroll
  for (int i=0;i<16;i++) acc[i] = zero;
  #pragma unroll
  for (int ks = 0; ks < 8; ks++){
    s16x8 a = *(const s16x8*)&Alds[16*w + lr][(32*ks + 8*lq) ^ ((lr&7)<<3)];
    #pragma unroll
    for (int ct = 0; ct < 16; ct++){
      s16x8 bw = *(const s16x8*)&W[(size_t)(16*ct + lr)*C_ + 32*ks + 8*lq];
      acc[ct] = __builtin_amdgcn_mfma_f32_16x16x32_bf16(a, bw, acc[ct], 0, 0, 0);
    }
  }
  if (z < 2){
    unsigned short* ob = (z==0 ? Qn : Kn) + ((size_t)b*N_ + nb)*C_;
    #pragma unroll
    for (int ct = 0; ct < 16; ct++){
      int o = 16*ct + lr;
      float bi = bias[o];
      #pragma unroll
      for (int r = 0; r < 4; r++){
        int row = 16*w + 4*lq + r;
        ob[(size_t)row*C_ + o] = f2bf(acc[ct][r] + bi);
      }
    }
  } else {
    __syncthreads();
    #pragma unroll
    for (int ct = 0; ct < 16; ct++){
      int o = 16*ct + lr;
      float bi = bias[o];
      #pragma unroll
      for (int r = 0; r < 4; r++)
        Tlds[16*w + 4*lq + r][o] = f2bf(acc[ct][r] + bi);
    }
    __syncthreads();
    unsigned short* vb = Vc + (size_t)b*C_*N_;
    int j = tid & 63, o0 = tid >> 6;
    #pragma unroll
    for (int o = o0; o < 256; o += 4)
      vb[(size_t)o*N_ + nb + j] = Tlds[j][o];
  }
}

// ---------------- attention: 16x16 frags, m-split 2, one dispatch round ----
// grid 512 x 256 thr = exactly 2 blocks/CU, ONE round (same makespan as the
// proven R15 schedule's two half-work rounds, but half the Opb/Ls partial
// traffic). LDS = K 16K + V 16K + beta dbuf 2x8K = 49152 B. Beta issued at
// top of compute (R15 schedule); P scratch aliases each wave's own 2KB
// row-slice of the CURRENT beta buffer (hazard chain validated R16/R18/R19).
__global__ __launch_bounds__(256, 3) void k_attn(
    const unsigned short* __restrict__ Qn, const unsigned short* __restrict__ Kn,
    const unsigned short* __restrict__ Vc, const float* __restrict__ beta,
    unsigned short* __restrict__ Opb, float* __restrict__ Ls)
{
  __shared__ __align__(16) char smem[49152];
  unsigned short* Klds = (unsigned short*)smem;             // 16 KB [32 m][256 c]
  unsigned short* Vt   = (unsigned short*)(smem + 16384);   // 16 KB [256 c][32 m]
  float*          Bl   = (float*)(smem + 32768);            // 2x8KB [64 q][32 m]
  const int tid = threadIdx.x;
  const int bid = blockIdx.x;
  const int b = bid & 7;
  const int jj = bid >> 3;                 // 0..63
  const int nt = jj & 31, mh = jj >> 5;    // nt 0..31, mh 0..1
  const int nb = nt*64;
  const unsigned short* Qb = Qn + (size_t)b*N_*C_;
  const unsigned short* Kb = Kn + (size_t)b*N_*C_;
  const unsigned short* Vb = Vc + (size_t)b*C_*N_;
  const float* betab = beta + (size_t)b*N_*N_;
  const int w = tid >> 6, lane = tid & 63, lr = lane & 15, lq = lane >> 4;
  const int wbase = (tid & ~63) * 16;

  // Q A-frags: qf[ks] = Q[nb+16w+lr][32ks+8lq .. +8]  (regs whole kernel)
  s16x8 qf[8];
  {
    const unsigned short* qp = Qb + (size_t)(nb + 16*w + lr)*C_ + 8*lq;
    #pragma unroll
    for (int ks = 0; ks < 8; ks++)
      qf[ks] = *(const s16x8*)&qp[32*ks];
  }
  f32x4 zero = {0.f,0.f,0.f,0.f};
  f32x4 oacc[16];
  #pragma unroll
  for (int i=0;i<16;i++) oacc[i] = zero;
  float psum[4] = {0.f,0.f,0.f,0.f};

// K: LDS[row][slot16B] = K[mb+row][(slot^(row&31))*8 .. +8)  (32 rows x 32 slots)
#define STAGEK(MB) { \
  _Pragma("unroll") \
  for (int rr=0; rr<4; rr++){ \
    const int o_ = rr*4096 + tid*16; \
    const int row_ = o_ >> 9; \
    const int slot_ = (o_ >> 4) & 31; \
    gload_lds16(Kb + (size_t)((MB)+row_)*C_ + ((slot_ ^ (row_&31))<<3), \
                (char*)Klds + rr*4096 + wbase); } }
// V: LDS[c][slot16B] = V[c][(MB) + (slot^(c&3))*8 .. +8)   (256 c x 4 slots)
#define STAGEV(MB) { \
  _Pragma("unroll") \
  for (int rr=0; rr<4; rr++){ \
    const int o_ = rr*4096 + tid*16; \
    const int c_ = o_ >> 6; \
    const int slot_ = (o_ >> 4) & 3; \
    gload_lds16(Vb + (size_t)c_*N_ + (MB) + ((slot_ ^ (c_&3))<<3), \
                (char*)Vt + rr*4096 + wbase); } }
// beta: buf[q][m] f32 linear   (64 q x 32 m = 8KB per buffer)
#define STAGEB(BUF, MB) { \
  _Pragma("unroll") \
  for (int rr=0; rr<2; rr++){ \
    const int o_ = rr*4096 + tid*16; \
    const int row_ = o_ >> 7; \
    const int g_ = (o_ >> 4) & 7; \
    gload_lds16(betab + (size_t)(nb+row_)*N_ + (MB) + g_*4, \
                (char*)Bl + (BUF)*8192 + rr*4096 + wbase); } }

  // prologue: K(0), V(0), beta(0)
  STAGEK(mh*1024)
  STAGEV(mh*1024)
  STAGEB(0, mh*1024)
  __syncthreads();

  for (int mt = 0; mt < 32; mt++){
    const int mb = mh*1024 + mt*32;
    // issue NEXT tile's beta into the other buffer (flies under compute)
    if (mt + 1 < 32){
      STAGEB((mt+1)&1, mb+32)
    }
    const float* Bp = Bl + (mt&1)*2048;   // current beta buffer (floats)
    // per-wave P scratch aliases THIS wave's 2KB row-slice of current buffer
    unsigned short* Pw = (unsigned short*)((char*)Bl + (mt&1)*8192 + w*2048);
    // beta(mt): this wave's own rows
    f32x4 bv[2];
    #pragma unroll
    for (int ct=0; ct<2; ct++){
      #pragma unroll
      for (int r=0; r<4; r++)
        bv[ct][r] = Bp[(16*w + 4*lq + r)*32 + 16*ct + lr];
    }
    // S = Q K^T : S[q=16w+4lq+r][m=16ct+lr]
    f32x4 sacc[2];
    sacc[0] = zero; sacc[1] = zero;
    __builtin_amdgcn_s_setprio(1);
    #pragma unroll
    for (int ks=0; ks<8; ks++){
      #pragma unroll
      for (int ct=0; ct<2; ct++){
        const int row = 16*ct + lr;
        const s16x8 kf = *(const s16x8*)
            &Klds[row*256 + (((4*ks + lq) ^ (row&31)) << 3)];
        sacc[ct] = __builtin_amdgcn_mfma_f32_16x16x32_bf16(qf[ks], kf, sacc[ct], 0,0,0);
      }
    }
    __builtin_amdgcn_s_setprio(0);
    // P = exp(S*beta); psum partial; pack to per-wave scratch (own beta rows,
    // safe: this thread's bv reads precede these writes in program order)
    #pragma unroll
    for (int ct=0; ct<2; ct++)
      #pragma unroll
      for (int r=0; r<4; r++){
        float p = __expf(sacc[ct][r] * bv[ct][r]);
        psum[r] += p;
        Pw[(4*lq + r)*40 + 16*ct + lr] = f2bf(p);
      }
    // PV: O[q][c] += P[q][m] V[c][m]   (K=32, one MFMA per ct)
    {
      const s16x8 pf = *(const s16x8*)&Pw[lr*40 + 8*lq];
      __builtin_amdgcn_s_setprio(1);
      #pragma unroll
      for (int ct=0; ct<16; ct++){
        const int c = 16*ct + lr;
        const s16x8 vf = *(const s16x8*)
            &Vt[c*32 + ((lq ^ (c&3)) << 3)];
        oacc[ct] = __builtin_amdgcn_mfma_f32_16x16x32_bf16(pf, vf, oacc[ct], 0,0,0);
      }
      __builtin_amdgcn_s_setprio(0);
    }
    // barrier A: all waves' LDS reads for tile mt done (VMEM queue untouched)
    asm volatile("s_waitcnt lgkmcnt(0)" ::: "memory");
    __builtin_amdgcn_s_barrier();
    if (mt + 1 < 32){
      STAGEK(mb + 32)
      STAGEV(mb + 32)
    }
    __syncthreads();   // drains K/V staging + the already-flown beta(t+1)
  }
#undef STAGEK
#undef STAGEV
#undef STAGEB

  // psum reduce over the 16-lane lr group (lanes share (w,lq) -> same q rows)
  #pragma unroll
  for (int r=0;r<4;r++){
    #pragma unroll
    for (int d=1; d<16; d<<=1) psum[r] += __shfl_xor(psum[r], d, 64);
  }
  // store unnormalized bf16 partials
  unsigned short* Ob = Opb + ((size_t)mh*8 + b)*(size_t)N_*C_;
  #pragma unroll
  for (int ct=0; ct<16; ct++){
    const int c = 16*ct + lr;
    #pragma unroll
    for (int r=0; r<4; r++){
      const int qo = nb + 16*w + 4*lq + r;
      Ob[(size_t)qo*C_ + c] = f2bf(oacc[ct][r]);
    }
  }
  if (lr == 0){
    float* Lb = Ls + ((size_t)mh*8 + b)*N_;
    #pragma unroll
    for (int r=0;r<4;r++) Lb[nb + 16*w + 4*lq + r] = psum[r];
  }
}

// ---------------- fused MLP: merge(2)+normalize -> conv1(BN,ReLU) -> conv2
// (BN,ReLU) -> conv3(+bias) -> residual add, all through LDS (overlaid).
__global__ __launch_bounds__(256) void k_mlpf(
    const unsigned short* __restrict__ Opb, const float* __restrict__ Ls,
    const unsigned short* __restrict__ W1, const float* __restrict__ sc1,
    const float* __restrict__ sh1,
    const unsigned short* __restrict__ W2, const float* __restrict__ sc2,
    const float* __restrict__ sh2,
    const unsigned short* __restrict__ W3, const float* __restrict__ b3,
    const float* __restrict__ x, float* __restrict__ out)
{
  __shared__ __align__(16) char smem[65792];
  unsigned short* Alds = (unsigned short*)smem;            // [64][256] @0 (phase1)
  unsigned short* H2   = (unsigned short*)(smem + 33024);  // [64][128]
  unsigned short* H1   = (unsigned short*)(smem + 49408);  // [64][128]
  float*          Dlds = (float*)smem;                     // [64][129] (phase3)
  int b = blockIdx.y, nt = blockIdx.x, nb = nt*64;
  int tid = threadIdx.x;
  const size_t PS = (size_t)8*N_*C_;
  for (int i = tid; i < 64*32; i += 256){
    int r = i >> 5, cv = i & 31;
    int row = nb + r;
    float ls = Ls[(size_t)b*N_ + row] + Ls[(size_t)(8+b)*N_ + row];
    float inv = 1.f / ls;
    size_t base = ((size_t)b*N_ + row)*C_ + cv*8;
    float a8[8] = {0.f,0.f,0.f,0.f,0.f,0.f,0.f,0.f};
    #pragma unroll
    for (int m=0;m<2;m++){
      s16x8 v = *(const s16x8*)&Opb[(size_t)m*PS + base];
      #pragma unroll
      for (int j=0;j<8;j++) a8[j] += bf2f((unsigned short)v[j]);
    }
    s16x8 o;
    #pragma unroll
    for (int j=0;j<8;j++) o[j] = (short)f2bf(a8[j] * inv);
    *(s16x8*)&Alds[r*256 + ((cv*8) ^ ((r&7)<<3))] = o;
  }
  __syncthreads();
  int w = tid >> 6, l = tid & 63, lr = l & 15, lq = l >> 4;
  f32x4 zero = {0.f,0.f,0.f,0.f};
  {
    f32x4 acc[8];
    #pragma unroll
    for (int i=0;i<8;i++) acc[i] = zero;
    #pragma unroll
    for (int ks = 0; ks < 8; ks++){
      s16x8 a = *(const s16x8*)&Alds[(16*w + lr)*256 + ((32*ks + 8*lq) ^ ((lr&7)<<3))];
      #pragma unroll
      for (int ct = 0; ct < 8; ct++){
        s16x8 bw = *(const s16x8*)&W1[(size_t)(16*ct + lr)*C_ + 32*ks + 8*lq];
        acc[ct] = __builtin_amdgcn_mfma_f32_16x16x32_bf16(a, bw, acc[ct], 0, 0, 0);
      }
    }
    __syncthreads();
    #pragma unroll
    for (int ct = 0; ct < 8; ct++){
      int o = 16*ct + lr;
      float s_ = sc1[o], h_ = sh1[o];
      #pragma unroll
      for (int r = 0; r < 4; r++){
        int row = 16*w + 4*lq + r;
        H1[row*128 + (o ^ ((row&7)<<3))] = f2bf(fmaxf(acc[ct][r]*s_ + h_, 0.f));
      }
    }
  }
  __syncthreads();
  {
    f32x4 acc[8];
    #pragma unroll
    for (int i=0;i<8;i++) acc[i] = zero;
    #pragma unroll
    for (int ks = 0; ks < 4; ks++){
      s16x8 a = *(const s16x8*)&H1[(16*w + lr)*128 + ((32*ks + 8*lq) ^ ((lr&7)<<3))];
      #pragma unroll
      for (int ct = 0; ct < 8; ct++){
        s16x8 bw = *(const s16x8*)&W2[(size_t)(16*ct + lr)*HC + 32*ks + 8*lq];
        acc[ct] = __builtin_amdgcn_mfma_f32_16x16x32_bf16(a, bw, acc[ct], 0, 0, 0);
      }
    }
    __syncthreads();
    #pragma unroll
    for (int ct = 0; ct < 8; ct++){
      int o = 16*ct + lr;
      float s_ = sc2[o], h_ = sh2[o];
      #pragma unroll
      for (int r = 0; r < 4; r++){
        int row = 16*w + 4*lq + r;
        H2[row*128 + (o ^ ((row&7)<<3))] = f2bf(fmaxf(acc[ct][r]*s_ + h_, 0.f));
      }
    }
  }
  __syncthreads();
  f32x4 acc[16];
  #pragma unroll
  for (int i=0;i<16;i++) acc[i] = zero;
  #pragma unroll
  for (int ks = 0; ks < 4; ks++){
    s16x8 a = *(const s16x8*)&H2[(16*w + lr)*128 + ((32*ks + 8*lq) ^ ((lr&7)<<3))];
    #pragma unroll
    for (int ct = 0; ct < 16; ct++){
      s16x8 bw = *(const s16x8*)&W3[(size_t)(16*ct + lr)*HC + 32*ks + 8*lq];
      acc[ct] = __builtin_amdgcn_mfma_f32_16x16x32_bf16(a, bw, acc[ct], 0, 0, 0);
    }
  }
  const float* xb = x + (size_t)b*C_*N_;
  float* ob = out + (size_t)b*C_*N_;
  int j = tid & 63, o0 = tid >> 6;
  #pragma unroll
  for (int half = 0; half < 2; half++){
    __syncthreads();
    #pragma unroll
    for (int ct = 8*half; ct < 8*half+8; ct++){
      int o = 16*ct + lr;
      float bi = b3[o];
      #pragma unroll
      for (int r = 0; r < 4; r++){
        int row = 16*w + 4*lq + r;
        Dlds[row*129 + (o - 128*half)] = acc[ct][r] + bi;
      }
    }
    __syncthreads();
    for (int o = 128*half + o0; o < 128*half + 128; o += 4)
      ob[(size_t)o*N_ + nb + j] = xb[(size_t)o*N_ + nb + j]
                                + Dlds[j*129 + (o - 128*half)];
  }
}

extern "C" void kernel_launch(void* const* d_in, const int* in_sizes, int n_in,
                              void* d_out, int out_size, void* d_ws, size_t ws_size,
                              hipStream_t stream)
{
  const float* x    = (const float*)d_in[0];
  const float* beta = (const float*)d_in[1];
  const float* wq = (const float*)d_in[2];  const float* bq = (const float*)d_in[3];
  const float* wk = (const float*)d_in[4];  const float* bk = (const float*)d_in[5];
  const float* wv = (const float*)d_in[6];  const float* bv = (const float*)d_in[7];
  const float* w1 = (const float*)d_in[8];  const float* b1 = (const float*)d_in[9];
  const float* g1 = (const float*)d_in[10]; const float* be1= (const float*)d_in[11];
  const float* m1 = (const float*)d_in[12]; const float* v1 = (const float*)d_in[13];
  const float* w2 = (const float*)d_in[14]; const float* b2 = (const float*)d_in[15];
  const float* g2 = (const float*)d_in[16]; const float* be2= (const float*)d_in[17];
  const float* m2 = (const float*)d_in[18]; const float* v2 = (const float*)d_in[19];
  const float* w3 = (const float*)d_in[20]; const float* b3 = (const float*)d_in[21];

  char* p = (char*)d_ws;
  auto alloc = [&](size_t n){ char* r = p; p += (n + 255) & ~(size_t)255; return r; };
  unsigned short* Qn  = (unsigned short*)alloc((size_t)B_*N_*C_*2);
  unsigned short* Kn  = (unsigned short*)alloc((size_t)B_*N_*C_*2);
  unsigned short* Vc  = (unsigned short*)alloc((size_t)B_*N_*C_*2);
  unsigned short* Opb = (unsigned short*)alloc((size_t)2*B_*N_*C_*2);
  float* Ls = (float*)alloc((size_t)2*B_*N_*4);
  unsigned short* wqb = (unsigned short*)alloc(65536*2);
  unsigned short* wkb = (unsigned short*)alloc(65536*2);
  unsigned short* wvb = (unsigned short*)alloc(65536*2);
  unsigned short* w1b = (unsigned short*)alloc(32768*2);
  unsigned short* w2b = (unsigned short*)alloc(16384*2);
  unsigned short* w3b = (unsigned short*)alloc(32768*2);
  float* sc1 = (float*)alloc(128*4);
  float* sh1 = (float*)alloc(128*4);
  float* sc2 = (float*)alloc(128*4);
  float* sh2 = (float*)alloc(128*4);

  PrepArgs pa;
  pa.s0 = wq; pa.s1 = wk; pa.s2 = wv; pa.s3 = w1; pa.s4 = w2; pa.s5 = w3;
  pa.d0 = wqb; pa.d1 = wkb; pa.d2 = wvb; pa.d3 = w1b; pa.d4 = w2b; pa.d5 = w3b;
  pa.b1 = b1; pa.g1 = g1; pa.be1 = be1; pa.m1 = m1; pa.v1 = v1;
  pa.b2 = b2; pa.g2 = g2; pa.be2 = be2; pa.m2 = m2; pa.v2 = v2;
  pa.sc1 = sc1; pa.sh1 = sh1; pa.sc2 = sc2; pa.sh2 = sh2;

  k_prep<<<dim3(1089), dim3(256), 0, stream>>>(pa);
  k_qkv<<<dim3(32, 8, 3), dim3(256), 0, stream>>>(x, wqb, wkb, wvb, bq, bk, bv, Qn, Kn, Vc);
  k_attn<<<dim3(512), dim3(256), 0, stream>>>(Qn, Kn, Vc, beta, Opb, Ls);
  k_mlpf<<<dim3(32, 8), dim3(256), 0, stream>>>(Opb, Ls, w1b, sc1, sh1,
                                                w2b, sc2, sh2, w3b, b3,
                                                x, (float*)d_out);
}

// Round 21
// 173.008 us; speedup vs baseline: 1.8912x; 1.0225x over previous
//
#include <hip/hip_runtime.h>
#include <stdint.h>

#define B_ 8
#define C_ 256
#define N_ 2048
#define HC 128

typedef float f32x4 __attribute__((ext_vector_type(4)));
typedef short s16x8 __attribute__((ext_vector_type(8)));

__device__ __forceinline__ unsigned short f2bf(float f){
  union { float f; unsigned u; } v; v.f = f;
  unsigned r = v.u + 0x7FFF + ((v.u >> 16) & 1u);
  return (unsigned short)(r >> 16);
}
__device__ __forceinline__ float bf2f(unsigned short u){
  union { unsigned u; float f; } v; v.u = ((unsigned)u) << 16;
  return v.f;
}
__device__ __forceinline__ void gload_lds16(const void* g, void* l){
  __builtin_amdgcn_global_load_lds(
      (const __attribute__((address_space(1))) unsigned int*)g,
      (__attribute__((address_space(3))) unsigned int*)l, 16, 0, 0);
}

// ---------------- prep: weights -> bf16, BN affine fold ----------------
struct PrepArgs {
  const float *s0,*s1,*s2,*s3,*s4,*s5;
  unsigned short *d0,*d1,*d2,*d3,*d4,*d5;
  const float *b1,*g1,*be1,*m1,*v1;
  const float *b2,*g2,*be2,*m2,*v2;
  float *sc1,*sh1,*sc2,*sh2;
};

__global__ __launch_bounds__(256) void k_prep(PrepArgs a){
  int gid = blockIdx.x*256 + threadIdx.x;
  const int S0=65536, S1=131072, S2=196608, S3=229376, S4=245760, S5=278528;
  if (gid < S0)      a.d0[gid]    = f2bf(a.s0[gid]);
  else if (gid < S1) a.d1[gid-S0] = f2bf(a.s1[gid-S0]);
  else if (gid < S2) a.d2[gid-S1] = f2bf(a.s2[gid-S1]);
  else if (gid < S3) a.d3[gid-S2] = f2bf(a.s3[gid-S2]);
  else if (gid < S4) a.d4[gid-S3] = f2bf(a.s4[gid-S3]);
  else if (gid < S5) a.d5[gid-S4] = f2bf(a.s5[gid-S4]);
  else if (gid < S5+128){
    int o = gid - S5;
    float inv = a.g1[o] * rsqrtf(a.v1[o] + 1e-5f);
    a.sc1[o] = inv;
    a.sh1[o] = a.b1[o]*inv + a.be1[o] - a.m1[o]*inv;
  } else if (gid < S5+256){
    int o = gid - S5 - 128;
    float inv = a.g2[o] * rsqrtf(a.v2[o] + 1e-5f);
    a.sc2[o] = inv;
    a.sh2[o] = a.b2[o]*inv + a.be2[o] - a.m2[o]*inv;
  }
}

// ---------------- fused: x-transpose + QKV GEMM (z-split for parallelism) ----
__global__ __launch_bounds__(256) void k_qkv(
    const float* __restrict__ x,
    const unsigned short* __restrict__ wqb, const unsigned short* __restrict__ wkb,
    const unsigned short* __restrict__ wvb,
    const float* __restrict__ bq, const float* __restrict__ bk, const float* __restrict__ bv,
    unsigned short* __restrict__ Qn, unsigned short* __restrict__ Kn,
    unsigned short* __restrict__ Vc)
{
  __shared__ unsigned short Alds[64][256];
  __shared__ unsigned short Tlds[64][260];
  int b = blockIdx.y, nt = blockIdx.x, z = blockIdx.z;
  int nb = nt*64;
  const float* xb = x + (size_t)b*C_*N_;
  int tid = threadIdx.x;
  float* Tf = (float*)&Tlds[0][0];   // [64][65]
  int tn = tid & 63, tq = tid >> 6;
  for (int c0 = 0; c0 < 256; c0 += 64){
    #pragma unroll
    for (int cc = tq; cc < 64; cc += 4)
      Tf[tn*65 + cc] = xb[(size_t)(c0+cc)*N_ + nb + tn];
    __syncthreads();
    #pragma unroll
    for (int nl = tq; nl < 64; nl += 4){
      int c = c0 + tn;
      Alds[nl][c ^ ((nl&7)<<3)] = f2bf(Tf[nl*65 + tn]);
    }
    __syncthreads();
  }
  int w = tid >> 6, l = tid & 63, lr = l & 15, lq = l >> 4;
  const unsigned short* W = (z==0) ? wqb : (z==1 ? wkb : wvb);
  const float* bias = (z==0) ? bq : (z==1 ? bk : bv);
  f32x4 zero = {0.f,0.f,0.f,0.f};
  f32x4 acc[16];
  #pragma unroll
  for (int i=0;i<16;i++) acc[i] = zero;
  #pragma unroll
  for (int ks = 0; ks < 8; ks++){
    s16x8 a = *(const s16x8*)&Alds[16*w + lr][(32*ks + 8*lq) ^ ((lr&7)<<3)];
    #pragma unroll
    for (int ct = 0; ct < 16; ct++){
      s16x8 bw = *(const s16x8*)&W[(size_t)(16*ct + lr)*C_ + 32*ks + 8*lq];
      acc[ct] = __builtin_amdgcn_mfma_f32_16x16x32_bf16(a, bw, acc[ct], 0, 0, 0);
    }
  }
  if (z < 2){
    unsigned short* ob = (z==0 ? Qn : Kn) + ((size_t)b*N_ + nb)*C_;
    #pragma unroll
    for (int ct = 0; ct < 16; ct++){
      int o = 16*ct + lr;
      float bi = bias[o];
      #pragma unroll
      for (int r = 0; r < 4; r++){
        int row = 16*w + 4*lq + r;
        ob[(size_t)row*C_ + o] = f2bf(acc[ct][r] + bi);
      }
    }
  } else {
    __syncthreads();
    #pragma unroll
    for (int ct = 0; ct < 16; ct++){
      int o = 16*ct + lr;
      float bi = bias[o];
      #pragma unroll
      for (int r = 0; r < 4; r++)
        Tlds[16*w + 4*lq + r][o] = f2bf(acc[ct][r] + bi);
    }
    __syncthreads();
    unsigned short* vb = Vc + (size_t)b*C_*N_;
    int j = tid & 63, o0 = tid >> 6;
    #pragma unroll
    for (int o = o0; o < 256; o += 4)
      vb[(size_t)o*N_ + nb + j] = Tlds[j][o];
  }
}

// ---------------- attention: 16x16 frags, q-tile 64, m-split 4 (R15 champion) ----
// grid 1024 x 256 thr, 2 blocks/CU (8 streaming waves -- measured optimum on
// the occupancy ladder: 8w=90us, 12w=102us, 16w=234us L2-thrash). Beta
// double-buffered, issued at top of compute; separate per-wave Plds.
__global__ __launch_bounds__(256, 3) void k_attn(
    const unsigned short* __restrict__ Qn, const unsigned short* __restrict__ Kn,
    const unsigned short* __restrict__ Vc, const float* __restrict__ beta,
    unsigned short* __restrict__ Opb, float* __restrict__ Ls)
{
  __shared__ __align__(16) char smem[54272];
  unsigned short* Klds = (unsigned short*)smem;             // 16 KB [32 m][256 c]
  unsigned short* Vt   = (unsigned short*)(smem + 16384);   // 16 KB [256 c][32 m]
  float*          Bl   = (float*)(smem + 32768);            // 2x8KB [64 q][32 m]
  unsigned short* Pl   = (unsigned short*)(smem + 49152);   // 4x[16][40] bf16
  const int tid = threadIdx.x;
  const int bid = blockIdx.x;
  const int b = bid & 7;
  const int jj = bid >> 3;                 // 0..127
  const int nt = jj & 31, mh = jj >> 5;    // nt 0..31, mh 0..3
  const int nb = nt*64;
  const unsigned short* Qb = Qn + (size_t)b*N_*C_;
  const unsigned short* Kb = Kn + (size_t)b*N_*C_;
  const unsigned short* Vb = Vc + (size_t)b*C_*N_;
  const float* betab = beta + (size_t)b*N_*N_;
  const int w = tid >> 6, lane = tid & 63, lr = lane & 15, lq = lane >> 4;
  const int wbase = (tid & ~63) * 16;
  unsigned short* Pw = Pl + w*16*40;

  // Q A-frags: qf[ks] = Q[nb+16w+lr][32ks+8lq .. +8]  (regs whole kernel)
  s16x8 qf[8];
  {
    const unsigned short* qp = Qb + (size_t)(nb + 16*w + lr)*C_ + 8*lq;
    #pragma unroll
    for (int ks = 0; ks < 8; ks++)
      qf[ks] = *(const s16x8*)&qp[32*ks];
  }
  f32x4 zero = {0.f,0.f,0.f,0.f};
  f32x4 oacc[16];
  #pragma unroll
  for (int i=0;i<16;i++) oacc[i] = zero;
  float psum[4] = {0.f,0.f,0.f,0.f};

// K: LDS[row][slot16B] = K[mb+row][(slot^(row&31))*8 .. +8)  (32 rows x 32 slots)
#define STAGEK(MB) { \
  _Pragma("unroll") \
  for (int rr=0; rr<4; rr++){ \
    const int o_ = rr*4096 + tid*16; \
    const int row_ = o_ >> 9; \
    const int slot_ = (o_ >> 4) & 31; \
    gload_lds16(Kb + (size_t)((MB)+row_)*C_ + ((slot_ ^ (row_&31))<<3), \
                (char*)Klds + rr*4096 + wbase); } }
// V: LDS[c][slot16B] = V[c][(MB) + (slot^(c&3))*8 .. +8)   (256 c x 4 slots)
#define STAGEV(MB) { \
  _Pragma("unroll") \
  for (int rr=0; rr<4; rr++){ \
    const int o_ = rr*4096 + tid*16; \
    const int c_ = o_ >> 6; \
    const int slot_ = (o_ >> 4) & 3; \
    gload_lds16(Vb + (size_t)c_*N_ + (MB) + ((slot_ ^ (c_&3))<<3), \
                (char*)Vt + rr*4096 + wbase); } }
// beta: buf[q][m] f32 linear   (64 q x 32 m = 8KB, 2 loads/thread)
#define STAGEB(BUF, MB) { \
  _Pragma("unroll") \
  for (int rr=0; rr<2; rr++){ \
    const int o_ = rr*4096 + tid*16; \
    const int row_ = o_ >> 7; \
    const int g_ = (o_ >> 4) & 7; \
    gload_lds16(betab + (size_t)(nb+row_)*N_ + (MB) + g_*4, \
                (char*)Bl + (BUF)*8192 + rr*4096 + wbase); } }

  // prologue: K(0), V(0), beta(0)
  STAGEK(mh*512)
  STAGEV(mh*512)
  STAGEB(0, mh*512)
  __syncthreads();

  for (int mt = 0; mt < 16; mt++){
    const int mb = mh*512 + mt*32;
    // issue NEXT tile's beta (flies under this tile's compute)
    if (mt + 1 < 16){
      STAGEB((mt+1)&1, mb+32)
    }
    const float* Bp = Bl + (mt&1)*2048;
    // S = Q K^T : S[q=16w+4lq+r][m=16ct+lr]
    f32x4 sacc[2];
    sacc[0] = zero; sacc[1] = zero;
    __builtin_amdgcn_s_setprio(1);
    #pragma unroll
    for (int ks=0; ks<8; ks++){
      #pragma unroll
      for (int ct=0; ct<2; ct++){
        const int row = 16*ct + lr;
        const s16x8 kf = *(const s16x8*)
            &Klds[row*256 + (((4*ks + lq) ^ (row&31)) << 3)];
        sacc[ct] = __builtin_amdgcn_mfma_f32_16x16x32_bf16(qf[ks], kf, sacc[ct], 0,0,0);
      }
    }
    __builtin_amdgcn_s_setprio(0);
    // P = exp(S*beta); psum partial; pack to per-wave Plds
    #pragma unroll
    for (int ct=0; ct<2; ct++)
      #pragma unroll
      for (int r=0; r<4; r++){
        float be = Bp[(16*w + 4*lq + r)*32 + 16*ct + lr];
        float p = __expf(sacc[ct][r] * be);
        psum[r] += p;
        Pw[(4*lq + r)*40 + 16*ct + lr] = f2bf(p);
      }
    // PV: O[q][c] += P[q][m] V[c][m]   (K=32, one MFMA per ct)
    {
      const s16x8 pf = *(const s16x8*)&Pw[lr*40 + 8*lq];
      __builtin_amdgcn_s_setprio(1);
      #pragma unroll
      for (int ct=0; ct<16; ct++){
        const int c = 16*ct + lr;
        const s16x8 vf = *(const s16x8*)
            &Vt[c*32 + ((lq ^ (c&3)) << 3)];
        oacc[ct] = __builtin_amdgcn_mfma_f32_16x16x32_bf16(pf, vf, oacc[ct], 0,0,0);
      }
      __builtin_amdgcn_s_setprio(0);
    }
    // barrier A: LDS reads done (VMEM queue untouched)
    asm volatile("s_waitcnt lgkmcnt(0)" ::: "memory");
    __builtin_amdgcn_s_barrier();
    if (mt + 1 < 16){
      STAGEK(mb + 32)
      STAGEV(mb + 32)
    }
    __syncthreads();   // drains K/V staging + already-flown beta(t+1)
  }
#undef STAGEK
#undef STAGEV
#undef STAGEB

  // psum reduce over the 16-lane lr group (lanes share (w,lq) -> same q rows)
  #pragma unroll
  for (int r=0;r<4;r++){
    #pragma unroll
    for (int d=1; d<16; d<<=1) psum[r] += __shfl_xor(psum[r], d, 64);
  }
  // store unnormalized bf16 partials
  unsigned short* Ob = Opb + ((size_t)mh*8 + b)*(size_t)N_*C_;
  #pragma unroll
  for (int ct=0; ct<16; ct++){
    const int c = 16*ct + lr;
    #pragma unroll
    for (int r=0; r<4; r++){
      const int qo = nb + 16*w + 4*lq + r;
      Ob[(size_t)qo*C_ + c] = f2bf(oacc[ct][r]);
    }
  }
  if (lr == 0){
    float* Lb = Ls + ((size_t)mh*8 + b)*N_;
    #pragma unroll
    for (int r=0;r<4;r++) Lb[nb + 16*w + 4*lq + r] = psum[r];
  }
}

// ---------------- fused MLP: merge(4)+normalize -> conv1(BN,ReLU) -> conv2
// (BN,ReLU) -> conv3(+bias) -> residual add, all through LDS (overlaid).
__global__ __launch_bounds__(256) void k_mlpf(
    const unsigned short* __restrict__ Opb, const float* __restrict__ Ls,
    const unsigned short* __restrict__ W1, const float* __restrict__ sc1,
    const float* __restrict__ sh1,
    const unsigned short* __restrict__ W2, const float* __restrict__ sc2,
    const float* __restrict__ sh2,
    const unsigned short* __restrict__ W3, const float* __restrict__ b3,
    const float* __restrict__ x, float* __restrict__ out)
{
  __shared__ __align__(16) char smem[65792];
  unsigned short* Alds = (unsigned short*)smem;            // [64][256] @0 (phase1)
  unsigned short* H2   = (unsigned short*)(smem + 33024);  // [64][128]
  unsigned short* H1   = (unsigned short*)(smem + 49408);  // [64][128]
  float*          Dlds = (float*)smem;                     // [64][129] (phase3)
  int b = blockIdx.y, nt = blockIdx.x, nb = nt*64;
  int tid = threadIdx.x;
  const size_t PS = (size_t)8*N_*C_;
  for (int i = tid; i < 64*32; i += 256){
    int r = i >> 5, cv = i & 31;
    int row = nb + r;
    float ls = Ls[(size_t)b*N_ + row] + Ls[(size_t)(8+b)*N_ + row]
             + Ls[(size_t)(16+b)*N_ + row] + Ls[(size_t)(24+b)*N_ + row];
    float inv = 1.f / ls;
    size_t base = ((size_t)b*N_ + row)*C_ + cv*8;
    float a8[8] = {0.f,0.f,0.f,0.f,0.f,0.f,0.f,0.f};
    #pragma unroll
    for (int m=0;m<4;m++){
      s16x8 v = *(const s16x8*)&Opb[(size_t)m*PS + base];
      #pragma unroll
      for (int j=0;j<8;j++) a8[j] += bf2f((unsigned short)v[j]);
    }
    s16x8 o;
    #pragma unroll
    for (int j=0;j<8;j++) o[j] = (short)f2bf(a8[j] * inv);
    *(s16x8*)&Alds[r*256 + ((cv*8) ^ ((r&7)<<3))] = o;
  }
  __syncthreads();
  int w = tid >> 6, l = tid & 63, lr = l & 15, lq = l >> 4;
  f32x4 zero = {0.f,0.f,0.f,0.f};
  {
    f32x4 acc[8];
    #pragma unroll
    for (int i=0;i<8;i++) acc[i] = zero;
    #pragma unroll
    for (int ks = 0; ks < 8; ks++){
      s16x8 a = *(const s16x8*)&Alds[(16*w + lr)*256 + ((32*ks + 8*lq) ^ ((lr&7)<<3))];
      #pragma unroll
      for (int ct = 0; ct < 8; ct++){
        s16x8 bw = *(const s16x8*)&W1[(size_t)(16*ct + lr)*C_ + 32*ks + 8*lq];
        acc[ct] = __builtin_amdgcn_mfma_f32_16x16x32_bf16(a, bw, acc[ct], 0, 0, 0);
      }
    }
    __syncthreads();
    #pragma unroll
    for (int ct = 0; ct < 8; ct++){
      int o = 16*ct + lr;
      float s_ = sc1[o], h_ = sh1[o];
      #pragma unroll
      for (int r = 0; r < 4; r++){
        int row = 16*w + 4*lq + r;
        H1[row*128 + (o ^ ((row&7)<<3))] = f2bf(fmaxf(acc[ct][r]*s_ + h_, 0.f));
      }
    }
  }
  __syncthreads();
  {
    f32x4 acc[8];
    #pragma unroll
    for (int i=0;i<8;i++) acc[i] = zero;
    #pragma unroll
    for (int ks = 0; ks < 4; ks++){
      s16x8 a = *(const s16x8*)&H1[(16*w + lr)*128 + ((32*ks + 8*lq) ^ ((lr&7)<<3))];
      #pragma unroll
      for (int ct = 0; ct < 8; ct++){
        s16x8 bw = *(const s16x8*)&W2[(size_t)(16*ct + lr)*HC + 32*ks + 8*lq];
        acc[ct] = __builtin_amdgcn_mfma_f32_16x16x32_bf16(a, bw, acc[ct], 0, 0, 0);
      }
    }
    __syncthreads();
    #pragma unroll
    for (int ct = 0; ct < 8; ct++){
      int o = 16*ct + lr;
      float s_ = sc2[o], h_ = sh2[o];
      #pragma unroll
      for (int r = 0; r < 4; r++){
        int row = 16*w + 4*lq + r;
        H2[row*128 + (o ^ ((row&7)<<3))] = f2bf(fmaxf(acc[ct][r]*s_ + h_, 0.f));
      }
    }
  }
  __syncthreads();
  f32x4 acc[16];
  #pragma unroll
  for (int i=0;i<16;i++) acc[i] = zero;
  #pragma unroll
  for (int ks = 0; ks < 4; ks++){
    s16x8 a = *(const s16x8*)&H2[(16*w + lr)*128 + ((32*ks + 8*lq) ^ ((lr&7)<<3))];
    #pragma unroll
    for (int ct = 0; ct < 16; ct++){
      s16x8 bw = *(const s16x8*)&W3[(size_t)(16*ct + lr)*HC + 32*ks + 8*lq];
      acc[ct] = __builtin_amdgcn_mfma_f32_16x16x32_bf16(a, bw, acc[ct], 0, 0, 0);
    }
  }
  const float* xb = x + (size_t)b*C_*N_;
  float* ob = out + (size_t)b*C_*N_;
  int j = tid & 63, o0 = tid >> 6;
  #pragma unroll
  for (int half = 0; half < 2; half++){
    __syncthreads();
    #pragma unroll
    for (int ct = 8*half; ct < 8*half+8; ct++){
      int o = 16*ct + lr;
      float bi = b3[o];
      #pragma unroll
      for (int r = 0; r < 4; r++){
        int row = 16*w + 4*lq + r;
        Dlds[row*129 + (o - 128*half)] = acc[ct][r] + bi;
      }
    }
    __syncthreads();
    for (int o = 128*half + o0; o < 128*half + 128; o += 4)
      ob[(size_t)o*N_ + nb + j] = xb[(size_t)o*N_ + nb + j]
                                + Dlds[j*129 + (o - 128*half)];
  }
}

extern "C" void kernel_launch(void* const* d_in, const int* in_sizes, int n_in,
                              void* d_out, int out_size, void* d_ws, size_t ws_size,
                              hipStream_t stream)
{
  const float* x    = (const float*)d_in[0];
  const float* beta = (const float*)d_in[1];
  const float* wq = (const float*)d_in[2];  const float* bq = (const float*)d_in[3];
  const float* wk = (const float*)d_in[4];  const float* bk = (const float*)d_in[5];
  const float* wv = (const float*)d_in[6];  const float* bv = (const float*)d_in[7];
  const float* w1 = (const float*)d_in[8];  const float* b1 = (const float*)d_in[9];
  const float* g1 = (const float*)d_in[10]; const float* be1= (const float*)d_in[11];
  const float* m1 = (const float*)d_in[12]; const float* v1 = (const float*)d_in[13];
  const float* w2 = (const float*)d_in[14]; const float* b2 = (const float*)d_in[15];
  const float* g2 = (const float*)d_in[16]; const float* be2= (const float*)d_in[17];
  const float* m2 = (const float*)d_in[18]; const float* v2 = (const float*)d_in[19];
  const float* w3 = (const float*)d_in[20]; const float* b3 = (const float*)d_in[21];

  char* p = (char*)d_ws;
  auto alloc = [&](size_t n){ char* r = p; p += (n + 255) & ~(size_t)255; return r; };
  unsigned short* Qn  = (unsigned short*)alloc((size_t)B_*N_*C_*2);
  unsigned short* Kn  = (unsigned short*)alloc((size_t)B_*N_*C_*2);
  unsigned short* Vc  = (unsigned short*)alloc((size_t)B_*N_*C_*2);
  unsigned short* Opb = (unsigned short*)alloc((size_t)4*B_*N_*C_*2);
  float* Ls = (float*)alloc((size_t)4*B_*N_*4);
  unsigned short* wqb = (unsigned short*)alloc(65536*2);
  unsigned short* wkb = (unsigned short*)alloc(65536*2);
  unsigned short* wvb = (unsigned short*)alloc(65536*2);
  unsigned short* w1b = (unsigned short*)alloc(32768*2);
  unsigned short* w2b = (unsigned short*)alloc(16384*2);
  unsigned short* w3b = (unsigned short*)alloc(32768*2);
  float* sc1 = (float*)alloc(128*4);
  float* sh1 = (float*)alloc(128*4);
  float* sc2 = (float*)alloc(128*4);
  float* sh2 = (float*)alloc(128*4);

  PrepArgs pa;
  pa.s0 = wq; pa.s1 = wk; pa.s2 = wv; pa.s3 = w1; pa.s4 = w2; pa.s5 = w3;
  pa.d0 = wqb; pa.d1 = wkb; pa.d2 = wvb; pa.d3 = w1b; pa.d4 = w2b; pa.d5 = w3b;
  pa.b1 = b1; pa.g1 = g1; pa.be1 = be1; pa.m1 = m1; pa.v1 = v1;
  pa.b2 = b2; pa.g2 = g2; pa.be2 = be2; pa.m2 = m2; pa.v2 = v2;
  pa.sc1 = sc1; pa.sh1 = sh1; pa.sc2 = sc2; pa.sh2 = sh2;

  k_prep<<<dim3(1089), dim3(256), 0, stream>>>(pa);
  k_qkv<<<dim3(32, 8, 3), dim3(256), 0, stream>>>(x, wqb, wkb, wvb, bq, bk, bv, Qn, Kn, Vc);
  k_attn<<<dim3(1024), dim3(256), 0, stream>>>(Qn, Kn, Vc, beta, Opb, Ls);
  k_mlpf<<<dim3(32, 8), dim3(256), 0, stream>>>(Opb, Ls, w1b, sc1, sh1,
                                                w2b, sc2, sh2, w3b, b3,
                                                x, (float*)d_out);
}